// Round 1
// baseline (486.223 us; speedup 1.0000x reference)
//
#include <hip/hip_runtime.h>
#include <math.h>

typedef unsigned short u16;
typedef __attribute__((ext_vector_type(8))) short short8;     // 8 bf16 = one MFMA A/B frag
typedef __attribute__((ext_vector_type(4))) float floatx4;    // MFMA C/D frag
typedef __attribute__((ext_vector_type(4))) unsigned short ushort4v;

// ---------- bf16 helpers (raw u16, RNE) ----------
__device__ __forceinline__ float bf2f(u16 x) {
    union { unsigned int u; float f; } v; v.u = ((unsigned int)x) << 16; return v.f;
}
__device__ __forceinline__ u16 f2bf(float f) {
    union { float f; unsigned int u; } v; v.f = f;
    unsigned int r = v.u + 0x7fffu + ((v.u >> 16) & 1u);
    return (u16)(r >> 16);
}

// ---------- async global->LDS, 16B per lane ----------
__device__ __forceinline__ void gl_lds16(const void* g, void* l) {
    __builtin_amdgcn_global_load_lds(
        (const __attribute__((address_space(1))) unsigned int*)g,
        (__attribute__((address_space(3))) unsigned int*)l,
        16, 0, 0);
}

// =====================================================================
// cast fp32 -> bf16, 4 elems/thread, exact-size grid
// =====================================================================
__global__ __launch_bounds__(256) void castbf(const float* __restrict__ src,
                                              u16* __restrict__ dst) {
    const size_t i = (size_t)blockIdx.x * 256 + threadIdx.x;
    const floatx4 v = *(const floatx4*)(src + i * 4);
    ushort4v o;
#pragma unroll
    for (int j = 0; j < 4; j++) o[j] = f2bf(v[j]);
    *(ushort4v*)(dst + i * 4) = o;
}

// =====================================================================
// transpose + cast 6 weight matrices: W[k][n] fp32 -> Wt[n][k] bf16
// =====================================================================
struct WTJobs { const float* src[6]; u16* dst[6]; };

__global__ __launch_bounds__(256) void wtrans(WTJobs wj) {
    __shared__ float tile[32][33];
    const int z = blockIdx.z;
    const float* W = wj.src[z];
    u16* Wt = wj.dst[z];
    const int n0 = blockIdx.x * 32, k0 = blockIdx.y * 32;
    const int tx = threadIdx.x & 31, ty = threadIdx.x >> 5;
#pragma unroll
    for (int i = 0; i < 4; i++)
        tile[ty + i * 8][tx] = W[(size_t)(k0 + ty + i * 8) * 1024 + n0 + tx];
    __syncthreads();
#pragma unroll
    for (int i = 0; i < 4; i++)
        Wt[(size_t)(n0 + ty + i * 8) * 1024 + k0 + tx] = f2bf(tile[tx][ty + i * 8]);
}

// =====================================================================
// GEMM: C[M,N] = A[M,K] @ B  (B given as Bt[N][K]) + bias[N]
// 128x128 tile, BK=32, 256 threads (4 waves, each 64x64), m97 structure.
// =====================================================================
struct GemmJob { const u16* A; const u16* Bt; const float* bias; u16* Cb; float* Cf; };
struct GemmJobs { GemmJob j[5]; };

__global__ __launch_bounds__(256, 2) void gemm_bt(GemmJobs jobs, int K, int N, int f32out) {
    __shared__ u16 As[128 * 32];
    __shared__ u16 Bs[128 * 32];
    const GemmJob jb = jobs.j[blockIdx.z];
    const int m0 = blockIdx.y * 128;
    const int n0 = blockIdx.x * 128;
    const int t = threadIdx.x;
    const int lane = t & 63;
    const int wid = t >> 6;
    const int wm = wid >> 1, wn = wid & 1;
    const int qd = lane >> 4, lm = lane & 15;

    const floatx4 zero4 = {0.f, 0.f, 0.f, 0.f};
    floatx4 acc[4][4];
#pragma unroll
    for (int i = 0; i < 4; i++)
#pragma unroll
        for (int j2 = 0; j2 < 4; j2++) acc[i][j2] = zero4;

    const u16* Ab = jb.A + (size_t)m0 * K;
    const u16* Bb = jb.Bt + (size_t)n0 * K;
    // staging decomposition: elem idx e = (i*256+t)*8 ; row = e>>5 ; kk = e&31
    const int e0 = t * 8;
    const int r0 = e0 >> 5, c0 = e0 & 31;
    const int e1 = (256 + t) * 8;
    const int r1 = e1 >> 5, c1 = e1 & 31;

    for (int k0 = 0; k0 < K; k0 += 32) {
        __syncthreads();
        gl_lds16(Ab + (size_t)r0 * K + k0 + c0, &As[e0]);
        gl_lds16(Ab + (size_t)r1 * K + k0 + c1, &As[e1]);
        gl_lds16(Bb + (size_t)r0 * K + k0 + c0, &Bs[e0]);
        gl_lds16(Bb + (size_t)r1 * K + k0 + c1, &Bs[e1]);
        __syncthreads();

        short8 af[4], bfg[4];
#pragma unroll
        for (int i = 0; i < 4; i++) {
            af[i]  = *(const short8*)&As[(wm * 64 + i * 16 + lm) * 32 + qd * 8];
            bfg[i] = *(const short8*)&Bs[(wn * 64 + i * 16 + lm) * 32 + qd * 8];
        }
#pragma unroll
        for (int i = 0; i < 4; i++)
#pragma unroll
            for (int j2 = 0; j2 < 4; j2++)
                acc[i][j2] = __builtin_amdgcn_mfma_f32_16x16x32_bf16(af[i], bfg[j2], acc[i][j2], 0, 0, 0);
    }

#pragma unroll
    for (int i = 0; i < 4; i++) {
        const int mb = m0 + wm * 64 + i * 16 + qd * 4;
#pragma unroll
        for (int j2 = 0; j2 < 4; j2++) {
            const int col = n0 + wn * 64 + j2 * 16 + lm;
            const float bv = jb.bias[col];
            const floatx4 c = acc[i][j2];
            if (f32out) {
#pragma unroll
                for (int r = 0; r < 4; r++)
                    jb.Cf[(size_t)(mb + r) * N + col] = c[r] + bv;
            } else {
#pragma unroll
                for (int r = 0; r < 4; r++)
                    jb.Cb[(size_t)(mb + r) * N + col] = f2bf(c[r] + bv);
            }
        }
    }
}

// =====================================================================
// gating: lam = sigmoid(xa.Wa + xb.Wb + ba + bb) per row; out = mix, bf16
// grid (4096 rows, 2): z=0 -> q path, z=1 -> k path. 256 thr, 4 elems each.
// =====================================================================
__global__ __launch_bounds__(256) void gating(
    const u16* __restrict__ qxp, const u16* __restrict__ qcp,
    const u16* __restrict__ kxp, const u16* __restrict__ kcp,
    const float* __restrict__ wVqx, const float* __restrict__ wVqc,
    const float* __restrict__ wVkx, const float* __restrict__ wVkc,
    const float* __restrict__ bVqx, const float* __restrict__ bVqc,
    const float* __restrict__ bVkx, const float* __restrict__ bVkc,
    u16* __restrict__ qg, u16* __restrict__ kg) {
    const int row = blockIdx.x;
    const int z = blockIdx.y;
    const u16* xa = z ? kxp : qxp;
    const u16* xb = z ? kcp : qcp;
    const float* wa = z ? wVkx : wVqx;
    const float* wb = z ? wVkc : wVqc;
    const float bsum = z ? (bVkx[0] + bVkc[0]) : (bVqx[0] + bVqc[0]);
    u16* out = z ? kg : qg;

    const int t = threadIdx.x;
    const size_t off = (size_t)row * 1024 + t * 4;
    const ushort4v av = *(const ushort4v*)(xa + off);
    const ushort4v bv = *(const ushort4v*)(xb + off);
    const floatx4 wav = *(const floatx4*)(wa + t * 4);
    const floatx4 wbv = *(const floatx4*)(wb + t * 4);
    float afl[4], bfl[4];
    float part = 0.f;
#pragma unroll
    for (int j = 0; j < 4; j++) {
        afl[j] = bf2f(av[j]); bfl[j] = bf2f(bv[j]);
        part += afl[j] * wav[j] + bfl[j] * wbv[j];
    }
#pragma unroll
    for (int m = 1; m <= 32; m <<= 1) part += __shfl_xor(part, m);
    __shared__ float red[4];
    if ((t & 63) == 0) red[t >> 6] = part;
    __syncthreads();
    const float tot = red[0] + red[1] + red[2] + red[3] + bsum;
    const float lam = 1.f / (1.f + exp2f(-tot * 1.44269504f));
    ushort4v ov;
#pragma unroll
    for (int j = 0; j < 4; j++) ov[j] = f2bf(afl[j] + lam * (bfl[j] - afl[j]));
    *(ushort4v*)(out + off) = ov;
}

// =====================================================================
// flash attention, bf16 MFMA, online softmax.
// grid (S/64=32 qtiles, B*H=32). block 256 = 4 waves, wave = 16 q-rows.
// K-tile = 32 keys. Ks[key][d] stride 72; Vt[d][key] stride 40; P stride 40.
// =====================================================================
__global__ __launch_bounds__(256, 2) void attn(
    const u16* __restrict__ Q, const u16* __restrict__ Kk,
    const u16* __restrict__ V, u16* __restrict__ O) {
    __shared__ u16 Ks[32 * 72];
    __shared__ u16 Vt[64 * 40];
    __shared__ u16 Ps[4 * 16 * 40];

    const int qt = blockIdx.x;
    const int bh = blockIdx.y;
    const int b = bh >> 4, h = bh & 15;
    const int base = b * 1024 + h * 64;   // elem offset inside a (s)-row pair
    const int t = threadIdx.x, lane = t & 63, w = t >> 6;
    const int qd = lane >> 4, lm = lane & 15;

    const int q0 = qt * 64;
    const u16* qrow = Q + (size_t)(q0 + w * 16 + lm) * 2048 + base;
    const short8 qf0 = *(const short8*)(qrow + qd * 8);
    const short8 qf1 = *(const short8*)(qrow + 32 + qd * 8);

    const floatx4 zero4 = {0.f, 0.f, 0.f, 0.f};
    floatx4 ctxa[4];
#pragma unroll
    for (int i = 0; i < 4; i++) ctxa[i] = zero4;
    float mrow[4], lrow[4];
#pragma unroll
    for (int r = 0; r < 4; r++) { mrow[r] = -__builtin_inff(); lrow[r] = 0.f; }

    u16* Pw = &Ps[w * 16 * 40];
    const float L2E = 1.44269504f;

    // staging index precompute
    const int sk_key = t >> 3, sk_dg = t & 7;     // K stage
    const int sv_key = t & 31, sv_dg = t >> 5;    // V stage

    for (int kt = 0; kt < 64; kt++) {
        __syncthreads();
        {   // K tile: 32 keys x 64 d, natural layout, pad stride 72
            const u16* src = Kk + (size_t)(kt * 32 + sk_key) * 2048 + base + sk_dg * 8;
            *(short8*)&Ks[sk_key * 72 + sk_dg * 8] = *(const short8*)src;
        }
        {   // V tile transposed: Vt[d][key], pad stride 40
            const u16* src = V + (size_t)(kt * 32 + sv_key) * 2048 + base + sv_dg * 8;
            const short8 vv = *(const short8*)src;
#pragma unroll
            for (int j = 0; j < 8; j++)
                Vt[(sv_dg * 8 + j) * 40 + sv_key] = (u16)vv[j];
        }
        __syncthreads();

        // scores: S[q=16][key=32], contraction over d=64
        floatx4 s0 = zero4, s1 = zero4;
        short8 kb;
        kb = *(const short8*)&Ks[lm * 72 + qd * 8];
        s0 = __builtin_amdgcn_mfma_f32_16x16x32_bf16(qf0, kb, s0, 0, 0, 0);
        kb = *(const short8*)&Ks[lm * 72 + 32 + qd * 8];
        s0 = __builtin_amdgcn_mfma_f32_16x16x32_bf16(qf1, kb, s0, 0, 0, 0);
        kb = *(const short8*)&Ks[(16 + lm) * 72 + qd * 8];
        s1 = __builtin_amdgcn_mfma_f32_16x16x32_bf16(qf0, kb, s1, 0, 0, 0);
        kb = *(const short8*)&Ks[(16 + lm) * 72 + 32 + qd * 8];
        s1 = __builtin_amdgcn_mfma_f32_16x16x32_bf16(qf1, kb, s1, 0, 0, 0);

        // online softmax per row (row = qd*4+r), reduce across 16 lanes of quad
        float p0[4], p1[4], alpha[4];
#pragma unroll
        for (int r = 0; r < 4; r++) {
            const float sa = s0[r] * 0.125f, sb = s1[r] * 0.125f;
            float mx = fmaxf(sa, sb);
            mx = fmaxf(mx, __shfl_xor(mx, 1));
            mx = fmaxf(mx, __shfl_xor(mx, 2));
            mx = fmaxf(mx, __shfl_xor(mx, 4));
            mx = fmaxf(mx, __shfl_xor(mx, 8));
            const float mnew = fmaxf(mrow[r], mx);
            const float al = exp2f((mrow[r] - mnew) * L2E);
            const float pa = exp2f((sa - mnew) * L2E);
            const float pb = exp2f((sb - mnew) * L2E);
            float ps = pa + pb;
            ps += __shfl_xor(ps, 1);
            ps += __shfl_xor(ps, 2);
            ps += __shfl_xor(ps, 4);
            ps += __shfl_xor(ps, 8);
            lrow[r] = lrow[r] * al + ps;
            mrow[r] = mnew;
            alpha[r] = al;
            p0[r] = pa; p1[r] = pb;
        }
#pragma unroll
        for (int nb = 0; nb < 4; nb++)
#pragma unroll
            for (int r = 0; r < 4; r++) ctxa[nb][r] *= alpha[r];

        // P: C-layout -> LDS [q][key] -> A-frag (wave-private, no barrier)
#pragma unroll
        for (int r = 0; r < 4; r++) {
            Pw[(qd * 4 + r) * 40 + lm]      = f2bf(p0[r]);
            Pw[(qd * 4 + r) * 40 + 16 + lm] = f2bf(p1[r]);
        }
        const short8 pf = *(const short8*)&Pw[lm * 40 + qd * 8];
#pragma unroll
        for (int nb = 0; nb < 4; nb++) {
            const short8 vb = *(const short8*)&Vt[(nb * 16 + lm) * 40 + qd * 8];
            ctxa[nb] = __builtin_amdgcn_mfma_f32_16x16x32_bf16(pf, vb, ctxa[nb], 0, 0, 0);
        }
    }

    // epilogue: ctx / l -> bf16 -> global [s*B+b][h*64+d]
#pragma unroll
    for (int r = 0; r < 4; r++) {
        const float inv = 1.0f / lrow[r];
        const int row = q0 + w * 16 + qd * 4 + r;
        u16* orow = O + (size_t)row * 2048 + base;
#pragma unroll
        for (int nb = 0; nb < 4; nb++)
            orow[nb * 16 + lm] = f2bf(ctxa[nb][r] * inv);
    }
}

// =====================================================================
// host orchestration
// =====================================================================
extern "C" void kernel_launch(void* const* d_in, const int* in_sizes, int n_in,
                              void* d_out, int out_size, void* d_ws, size_t ws_size,
                              hipStream_t stream) {
    const float* qx = (const float*)d_in[0];
    const float* kx = (const float*)d_in[1];
    const float* vx = (const float*)d_in[2];
    const float* qc = (const float*)d_in[3];
    const float* kc = (const float*)d_in[4];
    const float* W_qx = (const float*)d_in[5];   const float* b_qx = (const float*)d_in[6];
    const float* W_kx = (const float*)d_in[7];   const float* b_kx = (const float*)d_in[8];
    const float* W_vx = (const float*)d_in[9];   const float* b_vx = (const float*)d_in[10];
    const float* W_qc = (const float*)d_in[11];  const float* b_qc = (const float*)d_in[12];
    const float* W_kc = (const float*)d_in[13];  const float* b_kc = (const float*)d_in[14];
    const float* W_out = (const float*)d_in[15]; const float* b_out = (const float*)d_in[16];
    const float* W_Vqx = (const float*)d_in[17]; const float* b_Vqx = (const float*)d_in[18];
    const float* W_Vqc = (const float*)d_in[19]; const float* b_Vqc = (const float*)d_in[20];
    const float* W_Vkx = (const float*)d_in[21]; const float* b_Vkx = (const float*)d_in[22];
    const float* W_Vkc = (const float*)d_in[23]; const float* b_Vkc = (const float*)d_in[24];

    char* ws = (char*)d_ws;
    const size_t NT = 4194304;               // S*B*D elems
    const size_t XB_OFF = 0;                 // 5 x 8 MB bf16 inputs
    const size_t WT_OFF = XB_OFF + 5 * NT * 2;      // 6 x 2 MB bf16 Wt
    const size_t P_OFF  = WT_OFF + 6 * 2097152;     // 5 x 8 MB bf16 projections
    const size_t QG_OFF = P_OFF + 5 * NT * 2;
    const size_t KG_OFF = QG_OFF + NT * 2;
    const size_t CTX_OFF = KG_OFF + NT * 2;

    u16* Xb[5];
    for (int i = 0; i < 5; i++) Xb[i] = (u16*)(ws + XB_OFF + (size_t)i * NT * 2);
    u16* Wt[6];
    for (int i = 0; i < 6; i++) Wt[i] = (u16*)(ws + WT_OFF + (size_t)i * 2097152);
    u16* P[5];
    for (int i = 0; i < 5; i++) P[i] = (u16*)(ws + P_OFF + (size_t)i * NT * 2);
    u16* qg  = (u16*)(ws + QG_OFF);
    u16* kg  = (u16*)(ws + KG_OFF);
    u16* ctx = (u16*)(ws + CTX_OFF);

    // 1. cast inputs to bf16
    const float* srcs[5] = {qx, kx, vx, qc, kc};
    for (int i = 0; i < 5; i++)
        castbf<<<4096, 256, 0, stream>>>(srcs[i], Xb[i]);

    // 2. transpose + cast weights
    WTJobs wj;
    const float* wsrc[6] = {W_qx, W_kx, W_vx, W_qc, W_kc, W_out};
    for (int i = 0; i < 6; i++) { wj.src[i] = wsrc[i]; wj.dst[i] = Wt[i]; }
    wtrans<<<dim3(32, 32, 6), 256, 0, stream>>>(wj);

    // 3. five projection GEMMs (batched via grid.z)
    GemmJobs gj;
    const float* biases[5] = {b_qx, b_kx, b_vx, b_qc, b_kc};
    for (int i = 0; i < 5; i++) {
        gj.j[i].A = Xb[i]; gj.j[i].Bt = Wt[i]; gj.j[i].bias = biases[i];
        gj.j[i].Cb = P[i]; gj.j[i].Cf = nullptr;
    }
    gemm_bt<<<dim3(8, 32, 5), 256, 0, stream>>>(gj, 1024, 1024, 0);

    // 4. gating -> q, k (bf16)
    gating<<<dim3(4096, 2), 256, 0, stream>>>(P[0], P[3], P[1], P[4],
        W_Vqx, W_Vqc, W_Vkx, W_Vkc, b_Vqx, b_Vqc, b_Vkx, b_Vkc, qg, kg);

    // 5. attention
    attn<<<dim3(32, 32), 256, 0, stream>>>(qg, kg, P[2], ctx);

    // 6. output projection -> d_out (fp32)
    GemmJobs gf;
    for (int i = 0; i < 5; i++) {
        gf.j[i].A = ctx; gf.j[i].Bt = Wt[5]; gf.j[i].bias = b_out;
        gf.j[i].Cb = nullptr; gf.j[i].Cf = (float*)d_out;
    }
    gemm_bt<<<dim3(8, 32, 1), 256, 0, stream>>>(gf, 1024, 1024, 1);
}

// Round 2
// 390.176 us; speedup vs baseline: 1.2462x; 1.2462x over previous
//
#include <hip/hip_runtime.h>
#include <math.h>

typedef unsigned short u16;
typedef __attribute__((ext_vector_type(8))) short short8;     // 8 bf16 = one MFMA A/B frag
typedef __attribute__((ext_vector_type(4))) float floatx4;    // MFMA C/D frag
typedef __attribute__((ext_vector_type(4))) unsigned short ushort4v;
typedef __attribute__((ext_vector_type(2))) unsigned int uint2v;

// ---------- bf16 helpers (raw u16, RNE) ----------
__device__ __forceinline__ float bf2f(u16 x) {
    union { unsigned int u; float f; } v; v.u = ((unsigned int)x) << 16; return v.f;
}
__device__ __forceinline__ u16 f2bf(float f) {
    union { float f; unsigned int u; } v; v.f = f;
    unsigned int r = v.u + 0x7fffu + ((v.u >> 16) & 1u);
    return (u16)(r >> 16);
}
__device__ __forceinline__ unsigned int pk2bf(float a, float b) {
    return (unsigned int)f2bf(a) | ((unsigned int)f2bf(b) << 16);
}

// ---------- async global->LDS, 16B per lane ----------
__device__ __forceinline__ void gl_lds16(const void* g, void* l) {
    __builtin_amdgcn_global_load_lds(
        (const __attribute__((address_space(1))) unsigned int*)g,
        (__attribute__((address_space(3))) unsigned int*)l,
        16, 0, 0);
}

// =====================================================================
// cast fp32 -> bf16, batched over 5 tensors via grid.y
// =====================================================================
struct CastJobs { const float* src[5]; u16* dst[5]; };

__global__ __launch_bounds__(256) void castbf(CastJobs cj) {
    const int z = blockIdx.y;
    const size_t i = (size_t)blockIdx.x * 256 + threadIdx.x;
    const floatx4 v = *(const floatx4*)(cj.src[z] + i * 4);
    ushort4v o;
#pragma unroll
    for (int j = 0; j < 4; j++) o[j] = f2bf(v[j]);
    *(ushort4v*)(cj.dst[z] + i * 4) = o;
}

// =====================================================================
// transpose + cast 6 weight matrices: W[k][n] fp32 -> Wt[n][k] bf16
// =====================================================================
struct WTJobs { const float* src[6]; u16* dst[6]; };

__global__ __launch_bounds__(256) void wtrans(WTJobs wj) {
    __shared__ float tile[32][33];
    const int z = blockIdx.z;
    const float* W = wj.src[z];
    u16* Wt = wj.dst[z];
    const int n0 = blockIdx.x * 32, k0 = blockIdx.y * 32;
    const int tx = threadIdx.x & 31, ty = threadIdx.x >> 5;
#pragma unroll
    for (int i = 0; i < 4; i++)
        tile[ty + i * 8][tx] = W[(size_t)(k0 + ty + i * 8) * 1024 + n0 + tx];
    __syncthreads();
#pragma unroll
    for (int i = 0; i < 4; i++)
        Wt[(size_t)(n0 + ty + i * 8) * 1024 + k0 + tx] = f2bf(tile[tx][ty + i * 8]);
}

// =====================================================================
// transpose V: V[s][base+d] (stride 2048) -> Vtg[(bh*64+d)*2048 + s], bf16
// =====================================================================
__global__ __launch_bounds__(256) void vtrans(const u16* __restrict__ V,
                                              u16* __restrict__ Vtg) {
    __shared__ u16 tile[32][34];
    const int bh = blockIdx.z, b = bh >> 4, h = bh & 15;
    const int base = b * 1024 + h * 64;
    const int s0 = blockIdx.x * 32, d0 = blockIdx.y * 32;
    const int tx = threadIdx.x & 31, ty = threadIdx.x >> 5;
#pragma unroll
    for (int i = 0; i < 4; i++)
        tile[ty + i * 8][tx] = V[(size_t)(s0 + ty + i * 8) * 2048 + base + d0 + tx];
    __syncthreads();
#pragma unroll
    for (int i = 0; i < 4; i++)
        Vtg[((size_t)bh * 64 + d0 + ty + i * 8) * 2048 + s0 + tx] = tile[tx][ty + i * 8];
}

// =====================================================================
// GEMM: C[M,N] = A[M,K] @ B  (B given as Bt[N][K]) + bias[N]
// 128x128 tile, BK=32, 256 threads (4 waves, each 64x64), m97 structure.
// =====================================================================
struct GemmJob { const u16* A; const u16* Bt; const float* bias; u16* Cb; float* Cf; };
struct GemmJobs { GemmJob j[5]; };

__global__ __launch_bounds__(256, 2) void gemm_bt(GemmJobs jobs, int K, int N, int f32out) {
    __shared__ u16 As[128 * 32];
    __shared__ u16 Bs[128 * 32];
    const GemmJob jb = jobs.j[blockIdx.z];
    const int m0 = blockIdx.y * 128;
    const int n0 = blockIdx.x * 128;
    const int t = threadIdx.x;
    const int lane = t & 63;
    const int wid = t >> 6;
    const int wm = wid >> 1, wn = wid & 1;
    const int qd = lane >> 4, lm = lane & 15;

    const floatx4 zero4 = {0.f, 0.f, 0.f, 0.f};
    floatx4 acc[4][4];
#pragma unroll
    for (int i = 0; i < 4; i++)
#pragma unroll
        for (int j2 = 0; j2 < 4; j2++) acc[i][j2] = zero4;

    const u16* Ab = jb.A + (size_t)m0 * K;
    const u16* Bb = jb.Bt + (size_t)n0 * K;
    const int e0 = t * 8;
    const int r0 = e0 >> 5, c0 = e0 & 31;
    const int e1 = (256 + t) * 8;
    const int r1 = e1 >> 5, c1 = e1 & 31;

    for (int k0 = 0; k0 < K; k0 += 32) {
        __syncthreads();
        gl_lds16(Ab + (size_t)r0 * K + k0 + c0, &As[e0]);
        gl_lds16(Ab + (size_t)r1 * K + k0 + c1, &As[e1]);
        gl_lds16(Bb + (size_t)r0 * K + k0 + c0, &Bs[e0]);
        gl_lds16(Bb + (size_t)r1 * K + k0 + c1, &Bs[e1]);
        __syncthreads();

        short8 af[4], bfg[4];
#pragma unroll
        for (int i = 0; i < 4; i++) {
            af[i]  = *(const short8*)&As[(wm * 64 + i * 16 + lm) * 32 + qd * 8];
            bfg[i] = *(const short8*)&Bs[(wn * 64 + i * 16 + lm) * 32 + qd * 8];
        }
#pragma unroll
        for (int i = 0; i < 4; i++)
#pragma unroll
            for (int j2 = 0; j2 < 4; j2++)
                acc[i][j2] = __builtin_amdgcn_mfma_f32_16x16x32_bf16(af[i], bfg[j2], acc[i][j2], 0, 0, 0);
    }

#pragma unroll
    for (int i = 0; i < 4; i++) {
        const int mb = m0 + wm * 64 + i * 16 + qd * 4;
#pragma unroll
        for (int j2 = 0; j2 < 4; j2++) {
            const int col = n0 + wn * 64 + j2 * 16 + lm;
            const float bv = jb.bias[col];
            const floatx4 c = acc[i][j2];
            if (f32out) {
#pragma unroll
                for (int r = 0; r < 4; r++)
                    jb.Cf[(size_t)(mb + r) * N + col] = c[r] + bv;
            } else {
#pragma unroll
                for (int r = 0; r < 4; r++)
                    jb.Cb[(size_t)(mb + r) * N + col] = f2bf(c[r] + bv);
            }
        }
    }
}

// =====================================================================
// gating: lam = sigmoid(xa.Wa + xb.Wb + ba + bb) per row; out = mix, bf16
// =====================================================================
__global__ __launch_bounds__(256) void gating(
    const u16* __restrict__ qxp, const u16* __restrict__ qcp,
    const u16* __restrict__ kxp, const u16* __restrict__ kcp,
    const float* __restrict__ wVqx, const float* __restrict__ wVqc,
    const float* __restrict__ wVkx, const float* __restrict__ wVkc,
    const float* __restrict__ bVqx, const float* __restrict__ bVqc,
    const float* __restrict__ bVkx, const float* __restrict__ bVkc,
    u16* __restrict__ qg, u16* __restrict__ kg) {
    const int row = blockIdx.x;
    const int z = blockIdx.y;
    const u16* xa = z ? kxp : qxp;
    const u16* xb = z ? kcp : qcp;
    const float* wa = z ? wVkx : wVqx;
    const float* wb = z ? wVkc : wVqc;
    const float bsum = z ? (bVkx[0] + bVkc[0]) : (bVqx[0] + bVqc[0]);
    u16* out = z ? kg : qg;

    const int t = threadIdx.x;
    const size_t off = (size_t)row * 1024 + t * 4;
    const ushort4v av = *(const ushort4v*)(xa + off);
    const ushort4v bv = *(const ushort4v*)(xb + off);
    const floatx4 wav = *(const floatx4*)(wa + t * 4);
    const floatx4 wbv = *(const floatx4*)(wb + t * 4);
    float afl[4], bfl[4];
    float part = 0.f;
#pragma unroll
    for (int j = 0; j < 4; j++) {
        afl[j] = bf2f(av[j]); bfl[j] = bf2f(bv[j]);
        part += afl[j] * wav[j] + bfl[j] * wbv[j];
    }
#pragma unroll
    for (int m = 1; m <= 32; m <<= 1) part += __shfl_xor(part, m);
    __shared__ float red[4];
    if ((t & 63) == 0) red[t >> 6] = part;
    __syncthreads();
    const float tot = red[0] + red[1] + red[2] + red[3] + bsum;
    const float lam = 1.f / (1.f + exp2f(-tot * 1.44269504f));
    ushort4v ov;
#pragma unroll
    for (int j = 0; j < 4; j++) ov[j] = f2bf(afl[j] + lam * (bfl[j] - afl[j]));
    *(ushort4v*)(out + off) = ov;
}

// =====================================================================
// attention v2: S^T = K.Q^T (no-max exact softmax), P via vectorized LDS,
// PV from pre-transposed V. Wave = 32 q-rows, tile = 64 keys.
// grid (S/128=16, B*H=32). block 256 = 4 waves.
// All LDS strides 72 u16 (36 dwords == 4 mod 32 -> conflict-free frags).
// =====================================================================
__global__ __launch_bounds__(256, 2) void attn2(
    const u16* __restrict__ Q, const u16* __restrict__ Kk,
    const u16* __restrict__ Vtg, u16* __restrict__ O) {
    __shared__ u16 Ks[64 * 72];
    __shared__ u16 Vs[64 * 72];
    __shared__ u16 Ps[4 * 32 * 72];

    const int bh = blockIdx.y, b = bh >> 4, h = bh & 15;
    const int base = b * 1024 + h * 64;
    const int t = threadIdx.x, lane = t & 63, w = t >> 6;
    const int qd = lane >> 4, lm = lane & 15;
    const int q0 = blockIdx.x * 128 + w * 32;

    // Q B-frags: B[n=q][k=d] -> lane: q = qh*16+lm, d = c*32 + qd*8 ..+7
    short8 qf[2][2];
#pragma unroll
    for (int qh = 0; qh < 2; qh++) {
        const u16* qr = Q + (size_t)(q0 + qh * 16 + lm) * 2048 + base;
#pragma unroll
        for (int c = 0; c < 2; c++)
            qf[qh][c] = *(const short8*)(qr + c * 32 + qd * 8);
    }

    const floatx4 zero4 = {0.f, 0.f, 0.f, 0.f};
    floatx4 ctx[2][4];
#pragma unroll
    for (int qh = 0; qh < 2; qh++)
#pragma unroll
        for (int g = 0; g < 4; g++) ctx[qh][g] = zero4;
    float lpart[2] = {0.f, 0.f};

    u16* Pw = &Ps[w * 32 * 72];
    const float C = 0.18033688011112042f;   // log2(e)/sqrt(64)

    // staging: thread t moves 2x16B for K and V
    const int sr = t >> 3, sc = (t & 7) * 8;
    const u16* ksrc = Kk + (size_t)sr * 2048 + base + sc;            // + kt*64*2048
    const u16* vsrc = Vtg + ((size_t)bh * 64 + sr) * 2048 + sc;      // + kt*64
    u16* kdst0 = &Ks[sr * 72 + sc];
    u16* kdst1 = &Ks[(sr + 32) * 72 + sc];
    u16* vdst0 = &Vs[sr * 72 + sc];
    u16* vdst1 = &Vs[(sr + 32) * 72 + sc];

    for (int kt = 0; kt < 32; kt++) {
        __syncthreads();
        *(short8*)kdst0 = *(const short8*)ksrc;
        *(short8*)kdst1 = *(const short8*)(ksrc + (size_t)32 * 2048);
        *(short8*)vdst0 = *(const short8*)vsrc;
        *(short8*)vdst1 = *(const short8*)(vsrc + (size_t)32 * 2048);
        ksrc += (size_t)64 * 2048;
        vsrc += 64;
        __syncthreads();

        // --- S^T = K.Q^T, exp, P store (vectorized b64) ---
#pragma unroll
        for (int g = 0; g < 4; g++) {
            const short8 kf0 = *(const short8*)&Ks[(g * 16 + lm) * 72 + qd * 8];
            const short8 kf1 = *(const short8*)&Ks[(g * 16 + lm) * 72 + 32 + qd * 8];
#pragma unroll
            for (int qh = 0; qh < 2; qh++) {
                floatx4 st = zero4;
                st = __builtin_amdgcn_mfma_f32_16x16x32_bf16(kf0, qf[qh][0], st, 0, 0, 0);
                st = __builtin_amdgcn_mfma_f32_16x16x32_bf16(kf1, qf[qh][1], st, 0, 0, 0);
                // lane holds keys g*16 + qd*4 + r at q = qh*16+lm
                float p0 = exp2f(st[0] * C);
                float p1 = exp2f(st[1] * C);
                float p2 = exp2f(st[2] * C);
                float p3 = exp2f(st[3] * C);
                lpart[qh] += (p0 + p1) + (p2 + p3);
                uint2v pw;
                pw[0] = pk2bf(p0, p1);
                pw[1] = pk2bf(p2, p3);
                *(uint2v*)&Pw[(qh * 16 + lm) * 72 + g * 16 + qd * 4] = pw;
            }
        }

        // --- ctx += P.V ---
        short8 pa[2][2];
#pragma unroll
        for (int qh = 0; qh < 2; qh++)
#pragma unroll
            for (int c = 0; c < 2; c++)
                pa[qh][c] = *(const short8*)&Pw[(qh * 16 + lm) * 72 + c * 32 + qd * 8];
#pragma unroll
        for (int g = 0; g < 4; g++) {
            const short8 vb0 = *(const short8*)&Vs[(g * 16 + lm) * 72 + qd * 8];
            const short8 vb1 = *(const short8*)&Vs[(g * 16 + lm) * 72 + 32 + qd * 8];
#pragma unroll
            for (int qh = 0; qh < 2; qh++) {
                ctx[qh][g] = __builtin_amdgcn_mfma_f32_16x16x32_bf16(pa[qh][0], vb0, ctx[qh][g], 0, 0, 0);
                ctx[qh][g] = __builtin_amdgcn_mfma_f32_16x16x32_bf16(pa[qh][1], vb1, ctx[qh][g], 0, 0, 0);
            }
        }
    }

    // epilogue: l reduce (once), normalize, store bf16
#pragma unroll
    for (int qh = 0; qh < 2; qh++) {
        float l = lpart[qh];
        l += __shfl_xor(l, 16);
        l += __shfl_xor(l, 32);          // all lanes: full l for q = qh*16+lm
        float linv[4];
#pragma unroll
        for (int r = 0; r < 4; r++)
            linv[r] = 1.0f / __shfl(l, qd * 4 + r);   // l for row q = qh*16+qd*4+r
#pragma unroll
        for (int r = 0; r < 4; r++) {
            const int srow = q0 + qh * 16 + qd * 4 + r;
            u16* orow = O + (size_t)srow * 2048 + base;
#pragma unroll
            for (int g = 0; g < 4; g++)
                orow[g * 16 + lm] = f2bf(ctx[qh][g][r] * linv[r]);
        }
    }
}

// =====================================================================
// host orchestration
// =====================================================================
extern "C" void kernel_launch(void* const* d_in, const int* in_sizes, int n_in,
                              void* d_out, int out_size, void* d_ws, size_t ws_size,
                              hipStream_t stream) {
    const float* qx = (const float*)d_in[0];
    const float* kx = (const float*)d_in[1];
    const float* vx = (const float*)d_in[2];
    const float* qc = (const float*)d_in[3];
    const float* kc = (const float*)d_in[4];
    const float* W_qx = (const float*)d_in[5];   const float* b_qx = (const float*)d_in[6];
    const float* W_kx = (const float*)d_in[7];   const float* b_kx = (const float*)d_in[8];
    const float* W_vx = (const float*)d_in[9];   const float* b_vx = (const float*)d_in[10];
    const float* W_qc = (const float*)d_in[11];  const float* b_qc = (const float*)d_in[12];
    const float* W_kc = (const float*)d_in[13];  const float* b_kc = (const float*)d_in[14];
    const float* W_out = (const float*)d_in[15]; const float* b_out = (const float*)d_in[16];
    const float* W_Vqx = (const float*)d_in[17]; const float* b_Vqx = (const float*)d_in[18];
    const float* W_Vqc = (const float*)d_in[19]; const float* b_Vqc = (const float*)d_in[20];
    const float* W_Vkx = (const float*)d_in[21]; const float* b_Vkx = (const float*)d_in[22];
    const float* W_Vkc = (const float*)d_in[23]; const float* b_Vkc = (const float*)d_in[24];

    char* ws = (char*)d_ws;
    const size_t NT = 4194304;               // S*B*D elems
    const size_t XB_OFF = 0;                 // 5 x 8 MB bf16 inputs (dead after proj GEMM)
    const size_t WT_OFF = XB_OFF + 5 * NT * 2;      // 6 x 2 MB bf16 Wt
    const size_t P_OFF  = WT_OFF + 6 * 2097152;     // 5 x 8 MB bf16 projections
    const size_t QG_OFF = P_OFF + 5 * NT * 2;
    const size_t KG_OFF = QG_OFF + NT * 2;
    const size_t CTX_OFF = KG_OFF + NT * 2;

    u16* Xb[5];
    for (int i = 0; i < 5; i++) Xb[i] = (u16*)(ws + XB_OFF + (size_t)i * NT * 2);
    u16* Wt[6];
    for (int i = 0; i < 6; i++) Wt[i] = (u16*)(ws + WT_OFF + (size_t)i * 2097152);
    u16* P[5];
    for (int i = 0; i < 5; i++) P[i] = (u16*)(ws + P_OFF + (size_t)i * NT * 2);
    u16* qg  = (u16*)(ws + QG_OFF);
    u16* kg  = (u16*)(ws + KG_OFF);
    u16* ctx = (u16*)(ws + CTX_OFF);
    u16* Vtg = (u16*)(ws + XB_OFF);          // alias Xb[0] — dead by the time vtrans runs

    // 1. cast inputs to bf16 (batched)
    CastJobs cj;
    const float* srcs[5] = {qx, kx, vx, qc, kc};
    for (int i = 0; i < 5; i++) { cj.src[i] = srcs[i]; cj.dst[i] = Xb[i]; }
    castbf<<<dim3(4096, 5), 256, 0, stream>>>(cj);

    // 2. transpose + cast weights
    WTJobs wj;
    const float* wsrc[6] = {W_qx, W_kx, W_vx, W_qc, W_kc, W_out};
    for (int i = 0; i < 6; i++) { wj.src[i] = wsrc[i]; wj.dst[i] = Wt[i]; }
    wtrans<<<dim3(32, 32, 6), 256, 0, stream>>>(wj);

    // 3. five projection GEMMs (batched via grid.z)
    GemmJobs gj;
    const float* biases[5] = {b_qx, b_kx, b_vx, b_qc, b_kc};
    for (int i = 0; i < 5; i++) {
        gj.j[i].A = Xb[i]; gj.j[i].Bt = Wt[i]; gj.j[i].bias = biases[i];
        gj.j[i].Cb = P[i]; gj.j[i].Cf = nullptr;
    }
    gemm_bt<<<dim3(8, 32, 5), 256, 0, stream>>>(gj, 1024, 1024, 0);

    // 4. gating -> q, k (bf16)
    gating<<<dim3(4096, 2), 256, 0, stream>>>(P[0], P[3], P[1], P[4],
        W_Vqx, W_Vqc, W_Vkx, W_Vkc, b_Vqx, b_Vqc, b_Vkx, b_Vkc, qg, kg);

    // 5. transpose V for attention B-operand
    vtrans<<<dim3(64, 2, 32), 256, 0, stream>>>(P[2], Vtg);

    // 6. attention
    attn2<<<dim3(16, 32), 256, 0, stream>>>(qg, kg, Vtg, ctx);

    // 7. output projection -> d_out (fp32)
    GemmJobs gf;
    for (int i = 0; i < 5; i++) {
        gf.j[i].A = ctx; gf.j[i].Bt = Wt[5]; gf.j[i].bias = b_out;
        gf.j[i].Cb = nullptr; gf.j[i].Cf = (float*)d_out;
    }
    gemm_bt<<<dim3(8, 32, 1), 256, 0, stream>>>(gf, 1024, 1024, 1);
}

// Round 3
// 388.852 us; speedup vs baseline: 1.2504x; 1.0034x over previous
//
#include <hip/hip_runtime.h>
#include <math.h>

typedef unsigned short u16;
typedef __attribute__((ext_vector_type(8))) short short8;     // 8 bf16 = one MFMA A/B frag
typedef __attribute__((ext_vector_type(4))) float floatx4;    // MFMA C/D frag
typedef __attribute__((ext_vector_type(4))) unsigned short ushort4v;
typedef __attribute__((ext_vector_type(2))) unsigned int uint2v;

// ---------- bf16 helpers (raw u16, RNE) ----------
__device__ __forceinline__ float bf2f(u16 x) {
    union { unsigned int u; float f; } v; v.u = ((unsigned int)x) << 16; return v.f;
}
__device__ __forceinline__ u16 f2bf(float f) {
    union { float f; unsigned int u; } v; v.f = f;
    unsigned int r = v.u + 0x7fffu + ((v.u >> 16) & 1u);
    return (u16)(r >> 16);
}
__device__ __forceinline__ unsigned int pk2bf(float a, float b) {
#if __has_builtin(__builtin_amdgcn_cvt_pk_bf16_f32)
    auto r = __builtin_amdgcn_cvt_pk_bf16_f32(a, b);
    union { decltype(r) v; unsigned int u; } cv; cv.v = r; return cv.u;
#else
    return (unsigned int)f2bf(a) | ((unsigned int)f2bf(b) << 16);
#endif
}

// ---------- async global->LDS, 16B per lane ----------
__device__ __forceinline__ void gl_lds16(const void* g, void* l) {
    __builtin_amdgcn_global_load_lds(
        (const __attribute__((address_space(1))) unsigned int*)g,
        (__attribute__((address_space(3))) unsigned int*)l,
        16, 0, 0);
}

// =====================================================================
// wfuse: w_z[row] = dot(W_z[row][:], wv_z[:])  (fused gating weights)
// grid (64, 4): block 256 = 4 waves, wave handles 4 rows.
// =====================================================================
struct WFuseJobs { const float* W[4]; const float* wv[4]; float* out[4]; };

__global__ __launch_bounds__(256) void wfuse(WFuseJobs wf) {
    const int z = blockIdx.y;
    const float* W = wf.W[z];
    const float* wv = wf.wv[z];
    float* out = wf.out[z];
    const int lane = threadIdx.x & 63, w = threadIdx.x >> 6;
#pragma unroll
    for (int i = 0; i < 4; i++) {
        const int row = blockIdx.x * 16 + w * 4 + i;
        const float* Wr = W + (size_t)row * 1024 + lane * 16;
        const float* vr = wv + lane * 16;
        float p = 0.f;
#pragma unroll
        for (int c = 0; c < 4; c++) {
            const floatx4 a = *(const floatx4*)(Wr + c * 4);
            const floatx4 b = *(const floatx4*)(vr + c * 4);
            p += a[0] * b[0] + a[1] * b[1] + a[2] * b[2] + a[3] * b[3];
        }
#pragma unroll
        for (int m = 1; m <= 32; m <<= 1) p += __shfl_xor(p, m);
        if (lane == 0) out[row] = p;
    }
}

// =====================================================================
// cast fp32 -> bf16 (block = one 1024-elem row) + optional fused row-dot
// =====================================================================
struct CastJobs { const float* src[5]; u16* dst[5]; const float* w[5]; float* dot[5]; };

__global__ __launch_bounds__(256) void castbf(CastJobs cj) {
    const int z = blockIdx.y;
    const int row = blockIdx.x;
    const int t = threadIdx.x;
    const size_t i = (size_t)row * 256 + t;
    const floatx4 v = *(const floatx4*)(cj.src[z] + i * 4);
    ushort4v o;
#pragma unroll
    for (int j = 0; j < 4; j++) o[j] = f2bf(v[j]);
    *(ushort4v*)(cj.dst[z] + i * 4) = o;

    if (cj.w[z]) {
        const floatx4 wv = *(const floatx4*)(cj.w[z] + t * 4);
        float p = v[0] * wv[0] + v[1] * wv[1] + v[2] * wv[2] + v[3] * wv[3];
#pragma unroll
        for (int m = 1; m <= 32; m <<= 1) p += __shfl_xor(p, m);
        __shared__ float red[4];
        if ((t & 63) == 0) red[t >> 6] = p;
        __syncthreads();
        if (t == 0) cj.dot[z][row] = red[0] + red[1] + red[2] + red[3];
    }
}

// =====================================================================
// lamk: lam[row] = sigmoid(dA[row] + dB[row] + dot(b1,wv1)+dot(b2,wv2)+s1+s2)
// grid (16, 2): block 256, thread = one row.
// =====================================================================
struct LamJobs {
    const float* dA[2]; const float* dB[2];
    const float* b1[2]; const float* b2[2];
    const float* wv1[2]; const float* wv2[2];
    const float* s1[2]; const float* s2[2];
    float* lam[2];
};

__global__ __launch_bounds__(256) void lamk(LamJobs lj) {
    const int z = blockIdx.y;
    const int t = threadIdx.x;
    // block-redundant const: dot(b1,wv1)+dot(b2,wv2)
    float p = 0.f;
    {
        const floatx4 a1 = *(const floatx4*)(lj.b1[z] + t * 4);
        const floatx4 w1 = *(const floatx4*)(lj.wv1[z] + t * 4);
        const floatx4 a2 = *(const floatx4*)(lj.b2[z] + t * 4);
        const floatx4 w2 = *(const floatx4*)(lj.wv2[z] + t * 4);
#pragma unroll
        for (int j = 0; j < 4; j++) p += a1[j] * w1[j] + a2[j] * w2[j];
    }
#pragma unroll
    for (int m = 1; m <= 32; m <<= 1) p += __shfl_xor(p, m);
    __shared__ float red[4];
    if ((t & 63) == 0) red[t >> 6] = p;
    __syncthreads();
    const float c = red[0] + red[1] + red[2] + red[3] + lj.s1[z][0] + lj.s2[z][0];
    const int row = blockIdx.x * 256 + t;
    const float x = lj.dA[z][row] + lj.dB[z][row] + c;
    lj.lam[z][row] = 1.f / (1.f + exp2f(-x * 1.44269504f));
}

// =====================================================================
// transpose + cast 6 weight matrices: W[k][n] fp32 -> Wt[n][k] bf16
// =====================================================================
struct WTJobs { const float* src[6]; u16* dst[6]; };

__global__ __launch_bounds__(256) void wtrans(WTJobs wj) {
    __shared__ float tile[32][33];
    const int z = blockIdx.z;
    const float* W = wj.src[z];
    u16* Wt = wj.dst[z];
    const int n0 = blockIdx.x * 32, k0 = blockIdx.y * 32;
    const int tx = threadIdx.x & 31, ty = threadIdx.x >> 5;
#pragma unroll
    for (int i = 0; i < 4; i++)
        tile[ty + i * 8][tx] = W[(size_t)(k0 + ty + i * 8) * 1024 + n0 + tx];
    __syncthreads();
#pragma unroll
    for (int i = 0; i < 4; i++)
        Wt[(size_t)(n0 + ty + i * 8) * 1024 + k0 + tx] = f2bf(tile[tx][ty + i * 8]);
}

// =====================================================================
// transpose V: V[s][base+d] (stride 2048) -> Vtg[(bh*64+d)*2048 + s], bf16
// =====================================================================
__global__ __launch_bounds__(256) void vtrans(const u16* __restrict__ V,
                                              u16* __restrict__ Vtg) {
    __shared__ u16 tile[32][34];
    const int bh = blockIdx.z, b = bh >> 4, h = bh & 15;
    const int base = b * 1024 + h * 64;
    const int s0 = blockIdx.x * 32, d0 = blockIdx.y * 32;
    const int tx = threadIdx.x & 31, ty = threadIdx.x >> 5;
#pragma unroll
    for (int i = 0; i < 4; i++)
        tile[ty + i * 8][tx] = V[(size_t)(s0 + ty + i * 8) * 2048 + base + d0 + tx];
    __syncthreads();
#pragma unroll
    for (int i = 0; i < 4; i++)
        Vtg[((size_t)bh * 64 + d0 + ty + i * 8) * 2048 + s0 + tx] = tile[tx][ty + i * 8];
}

// =====================================================================
// plain GEMM: C[M,N] = A[M,K] @ Bt[N][K] + bias[N]; m97 structure
// =====================================================================
struct GemmJob { const u16* A; const u16* Bt; const float* bias; u16* Cb; float* Cf; };
struct GemmJobs { GemmJob j[1]; };

__global__ __launch_bounds__(256, 2) void gemm_bt(GemmJobs jobs, int K, int N, int f32out) {
    __shared__ u16 As[128 * 32];
    __shared__ u16 Bs[128 * 32];
    const GemmJob jb = jobs.j[blockIdx.z];
    const int m0 = blockIdx.y * 128;
    const int n0 = blockIdx.x * 128;
    const int t = threadIdx.x;
    const int lane = t & 63;
    const int wid = t >> 6;
    const int wm = wid >> 1, wn = wid & 1;
    const int qd = lane >> 4, lm = lane & 15;

    const floatx4 zero4 = {0.f, 0.f, 0.f, 0.f};
    floatx4 acc[4][4];
#pragma unroll
    for (int i = 0; i < 4; i++)
#pragma unroll
        for (int j2 = 0; j2 < 4; j2++) acc[i][j2] = zero4;

    const u16* Ab = jb.A + (size_t)m0 * K;
    const u16* Bb = jb.Bt + (size_t)n0 * K;
    const int e0 = t * 8;
    const int r0 = e0 >> 5, c0 = e0 & 31;
    const int e1 = (256 + t) * 8;
    const int r1 = e1 >> 5, c1 = e1 & 31;

    for (int k0 = 0; k0 < K; k0 += 32) {
        __syncthreads();
        gl_lds16(Ab + (size_t)r0 * K + k0 + c0, &As[e0]);
        gl_lds16(Ab + (size_t)r1 * K + k0 + c1, &As[e1]);
        gl_lds16(Bb + (size_t)r0 * K + k0 + c0, &Bs[e0]);
        gl_lds16(Bb + (size_t)r1 * K + k0 + c1, &Bs[e1]);
        __syncthreads();

        short8 af[4], bfg[4];
#pragma unroll
        for (int i = 0; i < 4; i++) {
            af[i]  = *(const short8*)&As[(wm * 64 + i * 16 + lm) * 32 + qd * 8];
            bfg[i] = *(const short8*)&Bs[(wn * 64 + i * 16 + lm) * 32 + qd * 8];
        }
#pragma unroll
        for (int i = 0; i < 4; i++)
#pragma unroll
            for (int j2 = 0; j2 < 4; j2++)
                acc[i][j2] = __builtin_amdgcn_mfma_f32_16x16x32_bf16(af[i], bfg[j2], acc[i][j2], 0, 0, 0);
    }

#pragma unroll
    for (int i = 0; i < 4; i++) {
        const int mb = m0 + wm * 64 + i * 16 + qd * 4;
#pragma unroll
        for (int j2 = 0; j2 < 4; j2++) {
            const int col = n0 + wn * 64 + j2 * 16 + lm;
            const float bv = jb.bias[col];
            const floatx4 c = acc[i][j2];
            if (f32out) {
#pragma unroll
                for (int r = 0; r < 4; r++)
                    jb.Cf[(size_t)(mb + r) * N + col] = c[r] + bv;
            } else {
#pragma unroll
                for (int r = 0; r < 4; r++)
                    jb.Cb[(size_t)(mb + r) * N + col] = f2bf(c[r] + bv);
            }
        }
    }
}

// =====================================================================
// fused projection + gating mix:
//   out = (1-lam)*(Aa@Ba^T + biasA) + lam*(Ac@Bc^T + biasC), bf16
// 128x128 tile, BK=32, dual accumulators. grid (8, 32, 2) z: 0=q, 1=k.
// =====================================================================
struct FuseJob {
    const u16* Aa; const u16* Ac; const u16* Ba; const u16* Bc;
    const float* biasA; const float* biasC; const float* lam; u16* out;
};
struct FuseJobs { FuseJob j[2]; };

__global__ __launch_bounds__(256, 2) void fusedproj(FuseJobs jobs) {
    __shared__ u16 Asa[128 * 32];
    __shared__ u16 Asc[128 * 32];
    __shared__ u16 Bsa[128 * 32];
    __shared__ u16 Bsc[128 * 32];
    const FuseJob jb = jobs.j[blockIdx.z];
    const int K = 1024;
    const int m0 = blockIdx.y * 128;
    const int n0 = blockIdx.x * 128;
    const int t = threadIdx.x;
    const int lane = t & 63;
    const int wid = t >> 6;
    const int wm = wid >> 1, wn = wid & 1;
    const int qd = lane >> 4, lm = lane & 15;

    const floatx4 zero4 = {0.f, 0.f, 0.f, 0.f};
    floatx4 accA[4][4], accC[4][4];
#pragma unroll
    for (int i = 0; i < 4; i++)
#pragma unroll
        for (int j2 = 0; j2 < 4; j2++) { accA[i][j2] = zero4; accC[i][j2] = zero4; }

    const u16* Aab = jb.Aa + (size_t)m0 * K;
    const u16* Acb = jb.Ac + (size_t)m0 * K;
    const u16* Bab = jb.Ba + (size_t)n0 * K;
    const u16* Bcb = jb.Bc + (size_t)n0 * K;
    const int e0 = t * 8;
    const int r0 = e0 >> 5, c0 = e0 & 31;
    const int e1 = (256 + t) * 8;
    const int r1 = e1 >> 5, c1 = e1 & 31;

    for (int k0 = 0; k0 < K; k0 += 32) {
        __syncthreads();
        gl_lds16(Aab + (size_t)r0 * K + k0 + c0, &Asa[e0]);
        gl_lds16(Aab + (size_t)r1 * K + k0 + c1, &Asa[e1]);
        gl_lds16(Acb + (size_t)r0 * K + k0 + c0, &Asc[e0]);
        gl_lds16(Acb + (size_t)r1 * K + k0 + c1, &Asc[e1]);
        gl_lds16(Bab + (size_t)r0 * K + k0 + c0, &Bsa[e0]);
        gl_lds16(Bab + (size_t)r1 * K + k0 + c1, &Bsa[e1]);
        gl_lds16(Bcb + (size_t)r0 * K + k0 + c0, &Bsc[e0]);
        gl_lds16(Bcb + (size_t)r1 * K + k0 + c1, &Bsc[e1]);
        __syncthreads();

        short8 aa[4], ac[4], ba[4], bc[4];
#pragma unroll
        for (int i = 0; i < 4; i++) {
            aa[i] = *(const short8*)&Asa[(wm * 64 + i * 16 + lm) * 32 + qd * 8];
            ac[i] = *(const short8*)&Asc[(wm * 64 + i * 16 + lm) * 32 + qd * 8];
            ba[i] = *(const short8*)&Bsa[(wn * 64 + i * 16 + lm) * 32 + qd * 8];
            bc[i] = *(const short8*)&Bsc[(wn * 64 + i * 16 + lm) * 32 + qd * 8];
        }
#pragma unroll
        for (int i = 0; i < 4; i++)
#pragma unroll
            for (int j2 = 0; j2 < 4; j2++) {
                accA[i][j2] = __builtin_amdgcn_mfma_f32_16x16x32_bf16(aa[i], ba[j2], accA[i][j2], 0, 0, 0);
                accC[i][j2] = __builtin_amdgcn_mfma_f32_16x16x32_bf16(ac[i], bc[j2], accC[i][j2], 0, 0, 0);
            }
    }

#pragma unroll
    for (int i = 0; i < 4; i++) {
        const int mb = m0 + wm * 64 + i * 16 + qd * 4;
        float lamv[4];
#pragma unroll
        for (int r = 0; r < 4; r++) lamv[r] = jb.lam[mb + r];
#pragma unroll
        for (int j2 = 0; j2 < 4; j2++) {
            const int col = n0 + wn * 64 + j2 * 16 + lm;
            const float bA = jb.biasA[col];
            const float bC = jb.biasC[col];
#pragma unroll
            for (int r = 0; r < 4; r++) {
                const float va = accA[i][j2][r] + bA;
                const float vc = accC[i][j2][r] + bC;
                jb.out[(size_t)(mb + r) * 1024 + col] = f2bf(va + lamv[r] * (vc - va));
            }
        }
    }
}

// =====================================================================
// attention v3: split-K flash (no-max exact softmax, additive partials).
// grid (16 qtiles, 32 bh, 2 splits). block 256 = 4 waves, wave = 32 q.
// Writes un-normalized ctx fp32 partials + l partials; merged later.
// =====================================================================
__global__ __launch_bounds__(256, 2) void attn3(
    const u16* __restrict__ Q, const u16* __restrict__ Kk,
    const u16* __restrict__ Vtg, float* __restrict__ ctxp,
    float* __restrict__ lp) {
    __shared__ u16 Ks[64 * 72];
    __shared__ u16 Vs[64 * 72];
    __shared__ u16 Ps[4 * 32 * 72];

    const int bh = blockIdx.y, b = bh >> 4, h = bh & 15;
    const int sp = blockIdx.z;
    const int base = b * 1024 + h * 64;
    const int t = threadIdx.x, lane = t & 63, w = t >> 6;
    const int qd = lane >> 4, lm = lane & 15;
    const int q0 = blockIdx.x * 128 + w * 32;

    short8 qf[2][2];
#pragma unroll
    for (int qh = 0; qh < 2; qh++) {
        const u16* qr = Q + (size_t)(q0 + qh * 16 + lm) * 2048 + base;
#pragma unroll
        for (int c = 0; c < 2; c++)
            qf[qh][c] = *(const short8*)(qr + c * 32 + qd * 8);
    }

    const floatx4 zero4 = {0.f, 0.f, 0.f, 0.f};
    floatx4 ctx[2][4];
#pragma unroll
    for (int qh = 0; qh < 2; qh++)
#pragma unroll
        for (int g = 0; g < 4; g++) ctx[qh][g] = zero4;
    float lpart[2] = {0.f, 0.f};

    u16* Pw = &Ps[w * 32 * 72];
    const float C = 0.18033688011112042f;   // log2(e)/sqrt(64)

    const int sr = t >> 3, sc = (t & 7) * 8;
    const u16* ksrc = Kk + (size_t)(sp * 1024 + sr) * 2048 + base + sc;
    const u16* vsrc = Vtg + ((size_t)bh * 64 + sr) * 2048 + sp * 1024 + sc;
    u16* kdst0 = &Ks[sr * 72 + sc];
    u16* kdst1 = &Ks[(sr + 32) * 72 + sc];
    u16* vdst0 = &Vs[sr * 72 + sc];
    u16* vdst1 = &Vs[(sr + 32) * 72 + sc];

    for (int kt = 0; kt < 16; kt++) {
        __syncthreads();
        *(short8*)kdst0 = *(const short8*)ksrc;
        *(short8*)kdst1 = *(const short8*)(ksrc + (size_t)32 * 2048);
        *(short8*)vdst0 = *(const short8*)vsrc;
        *(short8*)vdst1 = *(const short8*)(vsrc + (size_t)32 * 2048);
        ksrc += (size_t)64 * 2048;
        vsrc += 64;
        __syncthreads();

        // --- S^T = K.Q^T, exp, vectorized P store ---
#pragma unroll
        for (int g = 0; g < 4; g++) {
            const short8 kf0 = *(const short8*)&Ks[(g * 16 + lm) * 72 + qd * 8];
            const short8 kf1 = *(const short8*)&Ks[(g * 16 + lm) * 72 + 32 + qd * 8];
#pragma unroll
            for (int qh = 0; qh < 2; qh++) {
                floatx4 st = zero4;
                st = __builtin_amdgcn_mfma_f32_16x16x32_bf16(kf0, qf[qh][0], st, 0, 0, 0);
                st = __builtin_amdgcn_mfma_f32_16x16x32_bf16(kf1, qf[qh][1], st, 0, 0, 0);
                const float p0 = exp2f(st[0] * C);
                const float p1 = exp2f(st[1] * C);
                const float p2 = exp2f(st[2] * C);
                const float p3 = exp2f(st[3] * C);
                lpart[qh] += (p0 + p1) + (p2 + p3);
                uint2v pw;
                pw[0] = pk2bf(p0, p1);
                pw[1] = pk2bf(p2, p3);
                *(uint2v*)&Pw[(qh * 16 + lm) * 72 + g * 16 + qd * 4] = pw;
            }
        }

        // --- ctx += P.V ---
        short8 pa[2][2];
#pragma unroll
        for (int qh = 0; qh < 2; qh++)
#pragma unroll
            for (int c = 0; c < 2; c++)
                pa[qh][c] = *(const short8*)&Pw[(qh * 16 + lm) * 72 + c * 32 + qd * 8];
#pragma unroll
        for (int g = 0; g < 4; g++) {
            const short8 vb0 = *(const short8*)&Vs[(g * 16 + lm) * 72 + qd * 8];
            const short8 vb1 = *(const short8*)&Vs[(g * 16 + lm) * 72 + 32 + qd * 8];
#pragma unroll
            for (int qh = 0; qh < 2; qh++) {
                ctx[qh][g] = __builtin_amdgcn_mfma_f32_16x16x32_bf16(pa[qh][0], vb0, ctx[qh][g], 0, 0, 0);
                ctx[qh][g] = __builtin_amdgcn_mfma_f32_16x16x32_bf16(pa[qh][1], vb1, ctx[qh][g], 0, 0, 0);
            }
        }
    }

    // epilogue: store un-normalized partials
    float* cbase = ctxp + (size_t)sp * 4194304;
#pragma unroll
    for (int qh = 0; qh < 2; qh++) {
        float l = lpart[qh];
        l += __shfl_xor(l, 16);
        l += __shfl_xor(l, 32);
        if (lane < 16)
            lp[(size_t)sp * 65536 + bh * 2048 + q0 + qh * 16 + lane] = l;
#pragma unroll
        for (int r = 0; r < 4; r++) {
            const int srow = q0 + qh * 16 + qd * 4 + r;
            float* orow = cbase + (size_t)srow * 2048 + base;
#pragma unroll
            for (int g = 0; g < 4; g++)
                orow[g * 16 + lm] = ctx[qh][g][r];
        }
    }
}

// =====================================================================
// merge: out_bf16 = (ctx0 + ctx1) / (l0 + l1), elementwise over 4M
// =====================================================================
__global__ __launch_bounds__(256) void merge(const float* __restrict__ ctxp,
                                             const float* __restrict__ lp,
                                             u16* __restrict__ out) {
    const size_t idx = ((size_t)blockIdx.x * 256 + threadIdx.x) * 4;
    const floatx4 a = *(const floatx4*)(ctxp + idx);
    const floatx4 c = *(const floatx4*)(ctxp + 4194304 + idx);
    const int srow = (int)(idx >> 11);
    const int rem = (int)(idx & 2047);
    const int bh = rem >> 6;
    const float l = lp[bh * 2048 + srow] + lp[65536 + bh * 2048 + srow];
    const float inv = 1.0f / l;
    ushort4v o;
    const unsigned int lo = pk2bf((a[0] + c[0]) * inv, (a[1] + c[1]) * inv);
    const unsigned int hi = pk2bf((a[2] + c[2]) * inv, (a[3] + c[3]) * inv);
    o[0] = (u16)(lo & 0xffff); o[1] = (u16)(lo >> 16);
    o[2] = (u16)(hi & 0xffff); o[3] = (u16)(hi >> 16);
    *(ushort4v*)(out + idx) = o;
}

// =====================================================================
// host orchestration
// =====================================================================
extern "C" void kernel_launch(void* const* d_in, const int* in_sizes, int n_in,
                              void* d_out, int out_size, void* d_ws, size_t ws_size,
                              hipStream_t stream) {
    const float* qx = (const float*)d_in[0];
    const float* kx = (const float*)d_in[1];
    const float* vx = (const float*)d_in[2];
    const float* qc = (const float*)d_in[3];
    const float* kc = (const float*)d_in[4];
    const float* W_qx = (const float*)d_in[5];   const float* b_qx = (const float*)d_in[6];
    const float* W_kx = (const float*)d_in[7];   const float* b_kx = (const float*)d_in[8];
    const float* W_vx = (const float*)d_in[9];   const float* b_vx = (const float*)d_in[10];
    const float* W_qc = (const float*)d_in[11];  const float* b_qc = (const float*)d_in[12];
    const float* W_kc = (const float*)d_in[13];  const float* b_kc = (const float*)d_in[14];
    const float* W_out = (const float*)d_in[15]; const float* b_out = (const float*)d_in[16];
    const float* W_Vqx = (const float*)d_in[17]; const float* b_Vqx = (const float*)d_in[18];
    const float* W_Vqc = (const float*)d_in[19]; const float* b_Vqc = (const float*)d_in[20];
    const float* W_Vkx = (const float*)d_in[21]; const float* b_Vkx = (const float*)d_in[22];
    const float* W_Vkc = (const float*)d_in[23]; const float* b_Vkc = (const float*)d_in[24];

    char* ws = (char*)d_ws;
    const size_t NT = 4194304;               // S*B*D elems
    const size_t MB = 1048576;
    // layout (aliasing noted):
    //   0      .. 40 MB : Xb[5] bf16 (dead after proj) -> later ctx_part(0..32), Vtg(32..40)
    //   40 MB  .. 52 MB : Wt[6] bf16
    //   52 MB  .. 60 MB : Pv bf16 (dead after vtrans) -> (kept; ctxbf separate)
    //   60 MB  .. 68 MB : qg bf16
    //   68 MB  .. 76 MB : kg bf16
    //   76 MB  .. 84 MB : ctxbf bf16
    //   84 MB+ : wfused 16KB, dots 64KB, lam 32KB, l_part 512KB
    u16* Xb[5];
    for (int i = 0; i < 5; i++) Xb[i] = (u16*)(ws + (size_t)i * NT * 2);
    u16* Wt[6];
    for (int i = 0; i < 6; i++) Wt[i] = (u16*)(ws + 40 * MB + (size_t)i * 2 * MB);
    u16* Pv    = (u16*)(ws + 52 * MB);
    u16* qg    = (u16*)(ws + 60 * MB);
    u16* kg    = (u16*)(ws + 68 * MB);
    u16* ctxbf = (u16*)(ws + 76 * MB);
    float* wfused = (float*)(ws + 84 * MB);            // 4 x 1024
    float* dots   = (float*)(ws + 84 * MB + 16384);    // 4 x 4096
    float* lam    = (float*)(ws + 84 * MB + 16384 + 65536);   // 2 x 4096
    float* l_part = (float*)(ws + 84 * MB + 16384 + 65536 + 32768); // 2 x 32 x 2048
    float* ctxp = (float*)ws;                 // 32 MB, aliases Xb[0..3]
    u16* Vtg    = (u16*)(ws + 32 * MB);       // 8 MB, aliases Xb[4]

    // 1. fused gating weight vectors: w_z = W_z @ W_V_z
    WFuseJobs wf;
    wf.W[0] = W_qx; wf.wv[0] = W_Vqx; wf.out[0] = wfused;
    wf.W[1] = W_qc; wf.wv[1] = W_Vqc; wf.out[1] = wfused + 1024;
    wf.W[2] = W_kx; wf.wv[2] = W_Vkx; wf.out[2] = wfused + 2048;
    wf.W[3] = W_kc; wf.wv[3] = W_Vkc; wf.out[3] = wfused + 3072;
    wfuse<<<dim3(64, 4), 256, 0, stream>>>(wf);

    // 2. cast inputs to bf16 + fused lambda row-dots
    CastJobs cj;
    const float* srcs[5] = {qx, kx, vx, qc, kc};
    for (int i = 0; i < 5; i++) { cj.src[i] = srcs[i]; cj.dst[i] = Xb[i]; cj.w[i] = nullptr; cj.dot[i] = nullptr; }
    cj.w[0] = wfused;        cj.dot[0] = dots;            // qx . w1
    cj.w[3] = wfused + 1024; cj.dot[3] = dots + 4096;     // qc . w2
    cj.w[1] = wfused + 2048; cj.dot[1] = dots + 8192;     // kx . w3
    cj.w[4] = wfused + 3072; cj.dot[4] = dots + 12288;    // kc . w4
    castbf<<<dim3(4096, 5), 256, 0, stream>>>(cj);

    // 3. lambdas
    LamJobs lj;
    lj.dA[0] = dots;        lj.dB[0] = dots + 4096;
    lj.b1[0] = b_qx; lj.b2[0] = b_qc; lj.wv1[0] = W_Vqx; lj.wv2[0] = W_Vqc;
    lj.s1[0] = b_Vqx; lj.s2[0] = b_Vqc; lj.lam[0] = lam;
    lj.dA[1] = dots + 8192; lj.dB[1] = dots + 12288;
    lj.b1[1] = b_kx; lj.b2[1] = b_kc; lj.wv1[1] = W_Vkx; lj.wv2[1] = W_Vkc;
    lj.s1[1] = b_Vkx; lj.s2[1] = b_Vkc; lj.lam[1] = lam + 4096;
    lamk<<<dim3(16, 2), 256, 0, stream>>>(lj);

    // 4. transpose + cast weights
    WTJobs wj;
    const float* wsrc[6] = {W_qx, W_kx, W_vx, W_qc, W_kc, W_out};
    for (int i = 0; i < 6; i++) { wj.src[i] = wsrc[i]; wj.dst[i] = Wt[i]; }
    wtrans<<<dim3(32, 32, 6), 256, 0, stream>>>(wj);

    // 5. fused projection + mix -> qg, kg
    FuseJobs fj;
    fj.j[0].Aa = Xb[0]; fj.j[0].Ac = Xb[3]; fj.j[0].Ba = Wt[0]; fj.j[0].Bc = Wt[3];
    fj.j[0].biasA = b_qx; fj.j[0].biasC = b_qc; fj.j[0].lam = lam;        fj.j[0].out = qg;
    fj.j[1].Aa = Xb[1]; fj.j[1].Ac = Xb[4]; fj.j[1].Ba = Wt[1]; fj.j[1].Bc = Wt[4];
    fj.j[1].biasA = b_kx; fj.j[1].biasC = b_kc; fj.j[1].lam = lam + 4096; fj.j[1].out = kg;
    fusedproj<<<dim3(8, 32, 2), 256, 0, stream>>>(fj);

    // 6. v projection
    GemmJobs gv;
    gv.j[0].A = Xb[2]; gv.j[0].Bt = Wt[2]; gv.j[0].bias = b_vx;
    gv.j[0].Cb = Pv; gv.j[0].Cf = nullptr;
    gemm_bt<<<dim3(8, 32, 1), 256, 0, stream>>>(gv, 1024, 1024, 0);

    // 7. transpose V
    vtrans<<<dim3(64, 2, 32), 256, 0, stream>>>(Pv, Vtg);

    // 8. attention (split-K x2)
    attn3<<<dim3(16, 32, 2), 256, 0, stream>>>(qg, kg, Vtg, ctxp, l_part);

    // 9. merge partials -> ctx bf16
    merge<<<4096, 256, 0, stream>>>(ctxp, l_part, ctxbf);

    // 10. output projection -> d_out (fp32)
    GemmJobs gf;
    gf.j[0].A = ctxbf; gf.j[0].Bt = Wt[5]; gf.j[0].bias = b_out;
    gf.j[0].Cb = nullptr; gf.j[0].Cf = (float*)d_out;
    gemm_bt<<<dim3(8, 32, 1), 256, 0, stream>>>(gf, 1024, 1024, 1);
}

// Round 4
// 366.844 us; speedup vs baseline: 1.3254x; 1.0600x over previous
//
#include <hip/hip_runtime.h>
#include <math.h>

typedef unsigned short u16;
typedef __attribute__((ext_vector_type(8))) short short8;     // 8 bf16 = one MFMA A/B frag
typedef __attribute__((ext_vector_type(4))) float floatx4;    // MFMA C/D frag
typedef __attribute__((ext_vector_type(4))) unsigned short ushort4v;
typedef __attribute__((ext_vector_type(2))) unsigned int uint2v;

// ---------- bf16 helpers (raw u16, RNE) ----------
__device__ __forceinline__ float bf2f(u16 x) {
    union { unsigned int u; float f; } v; v.u = ((unsigned int)x) << 16; return v.f;
}
__device__ __forceinline__ u16 f2bf(float f) {
    union { float f; unsigned int u; } v; v.f = f;
    unsigned int r = v.u + 0x7fffu + ((v.u >> 16) & 1u);
    return (u16)(r >> 16);
}
__device__ __forceinline__ unsigned int pk2bf(float a, float b) {
#if __has_builtin(__builtin_amdgcn_cvt_pk_bf16_f32)
    auto r = __builtin_amdgcn_cvt_pk_bf16_f32(a, b);
    union { decltype(r) v; unsigned int u; } cv; cv.v = r; return cv.u;
#else
    return (unsigned int)f2bf(a) | ((unsigned int)f2bf(b) << 16);
#endif
}

// ---------- async global->LDS, 16B per lane ----------
__device__ __forceinline__ void gl_lds16(const void* g, void* l) {
    __builtin_amdgcn_global_load_lds(
        (const __attribute__((address_space(1))) unsigned int*)g,
        (__attribute__((address_space(3))) unsigned int*)l,
        16, 0, 0);
}

// =====================================================================
// wfuse: w_z[row] = dot(W_z[row][:], wv_z[:])  (fused gating weights)
// =====================================================================
struct WFuseJobs { const float* W[4]; const float* wv[4]; float* out[4]; };

__global__ __launch_bounds__(256) void wfuse(WFuseJobs wf) {
    const int z = blockIdx.y;
    const float* W = wf.W[z];
    const float* wv = wf.wv[z];
    float* out = wf.out[z];
    const int lane = threadIdx.x & 63, w = threadIdx.x >> 6;
#pragma unroll
    for (int i = 0; i < 4; i++) {
        const int row = blockIdx.x * 16 + w * 4 + i;
        const float* Wr = W + (size_t)row * 1024 + lane * 16;
        const float* vr = wv + lane * 16;
        float p = 0.f;
#pragma unroll
        for (int c = 0; c < 4; c++) {
            const floatx4 a = *(const floatx4*)(Wr + c * 4);
            const floatx4 b = *(const floatx4*)(vr + c * 4);
            p += a[0] * b[0] + a[1] * b[1] + a[2] * b[2] + a[3] * b[3];
        }
#pragma unroll
        for (int m = 1; m <= 32; m <<= 1) p += __shfl_xor(p, m);
        if (lane == 0) out[row] = p;
    }
}

// =====================================================================
// cast fp32 -> bf16 (block = one 1024-elem row) + optional fused row-dot
// =====================================================================
struct CastJobs { const float* src[5]; u16* dst[5]; const float* w[5]; float* dot[5]; };

__global__ __launch_bounds__(256) void castbf(CastJobs cj) {
    const int z = blockIdx.y;
    const int row = blockIdx.x;
    const int t = threadIdx.x;
    const size_t i = (size_t)row * 256 + t;
    const floatx4 v = *(const floatx4*)(cj.src[z] + i * 4);
    ushort4v o;
#pragma unroll
    for (int j = 0; j < 4; j++) o[j] = f2bf(v[j]);
    *(ushort4v*)(cj.dst[z] + i * 4) = o;

    if (cj.w[z]) {
        const floatx4 wv = *(const floatx4*)(cj.w[z] + t * 4);
        float p = v[0] * wv[0] + v[1] * wv[1] + v[2] * wv[2] + v[3] * wv[3];
#pragma unroll
        for (int m = 1; m <= 32; m <<= 1) p += __shfl_xor(p, m);
        __shared__ float red[4];
        if ((t & 63) == 0) red[t >> 6] = p;
        __syncthreads();
        if (t == 0) cj.dot[z][row] = red[0] + red[1] + red[2] + red[3];
    }
}

// =====================================================================
// lamk: lam[row] = sigmoid(dA[row] + dB[row] + const)
// =====================================================================
struct LamJobs {
    const float* dA[2]; const float* dB[2];
    const float* b1[2]; const float* b2[2];
    const float* wv1[2]; const float* wv2[2];
    const float* s1[2]; const float* s2[2];
    float* lam[2];
};

__global__ __launch_bounds__(256) void lamk(LamJobs lj) {
    const int z = blockIdx.y;
    const int t = threadIdx.x;
    float p = 0.f;
    {
        const floatx4 a1 = *(const floatx4*)(lj.b1[z] + t * 4);
        const floatx4 w1 = *(const floatx4*)(lj.wv1[z] + t * 4);
        const floatx4 a2 = *(const floatx4*)(lj.b2[z] + t * 4);
        const floatx4 w2 = *(const floatx4*)(lj.wv2[z] + t * 4);
#pragma unroll
        for (int j = 0; j < 4; j++) p += a1[j] * w1[j] + a2[j] * w2[j];
    }
#pragma unroll
    for (int m = 1; m <= 32; m <<= 1) p += __shfl_xor(p, m);
    __shared__ float red[4];
    if ((t & 63) == 0) red[t >> 6] = p;
    __syncthreads();
    const float c = red[0] + red[1] + red[2] + red[3] + lj.s1[z][0] + lj.s2[z][0];
    const int row = blockIdx.x * 256 + t;
    const float x = lj.dA[z][row] + lj.dB[z][row] + c;
    lj.lam[z][row] = 1.f / (1.f + exp2f(-x * 1.44269504f));
}

// =====================================================================
// transpose + cast 6 weight matrices: W[k][n] fp32 -> Wt[n][k] bf16
// =====================================================================
struct WTJobs { const float* src[6]; u16* dst[6]; };

__global__ __launch_bounds__(256) void wtrans(WTJobs wj) {
    __shared__ float tile[32][33];
    const int z = blockIdx.z;
    const float* W = wj.src[z];
    u16* Wt = wj.dst[z];
    const int n0 = blockIdx.x * 32, k0 = blockIdx.y * 32;
    const int tx = threadIdx.x & 31, ty = threadIdx.x >> 5;
#pragma unroll
    for (int i = 0; i < 4; i++)
        tile[ty + i * 8][tx] = W[(size_t)(k0 + ty + i * 8) * 1024 + n0 + tx];
    __syncthreads();
#pragma unroll
    for (int i = 0; i < 4; i++)
        Wt[(size_t)(n0 + ty + i * 8) * 1024 + k0 + tx] = f2bf(tile[tx][ty + i * 8]);
}

// =====================================================================
// transpose V: V[s][base+d] (stride 2048) -> Vtg[(bh*64+d)*2048 + s], bf16
// =====================================================================
__global__ __launch_bounds__(256) void vtrans(const u16* __restrict__ V,
                                              u16* __restrict__ Vtg) {
    __shared__ u16 tile[32][34];
    const int bh = blockIdx.z, b = bh >> 4, h = bh & 15;
    const int base = b * 1024 + h * 64;
    const int s0 = blockIdx.x * 32, d0 = blockIdx.y * 32;
    const int tx = threadIdx.x & 31, ty = threadIdx.x >> 5;
#pragma unroll
    for (int i = 0; i < 4; i++)
        tile[ty + i * 8][tx] = V[(size_t)(s0 + ty + i * 8) * 2048 + base + d0 + tx];
    __syncthreads();
#pragma unroll
    for (int i = 0; i < 4; i++)
        Vtg[((size_t)bh * 64 + d0 + ty + i * 8) * 2048 + s0 + tx] = tile[tx][ty + i * 8];
}

// =====================================================================
// projall: unified projection GEMMs, 128x128 tile, BK=32.
// dual mode (Ac != null): out = (1-lam)*(Aa@Ba^T+biasA) + lam*(Ac@Bc^T+biasC)
// single mode:            out = Aa@Ba^T + biasA
// grid (8, 32, 3): z=0 q-dual, z=1 k-dual, z=2 v-single.
// =====================================================================
struct PJob {
    const u16* Aa; const u16* Ac; const u16* Ba; const u16* Bc;
    const float* biasA; const float* biasC; const float* lam; u16* out;
};
struct PJobs { PJob j[3]; };

__global__ __launch_bounds__(256, 2) void projall(PJobs jobs) {
    __shared__ u16 Asa[128 * 32];
    __shared__ u16 Asc[128 * 32];
    __shared__ u16 Bsa[128 * 32];
    __shared__ u16 Bsc[128 * 32];
    const PJob jb = jobs.j[blockIdx.z];
    const int K = 1024;
    const int m0 = blockIdx.y * 128;
    const int n0 = blockIdx.x * 128;
    const int t = threadIdx.x;
    const int lane = t & 63;
    const int wid = t >> 6;
    const int wm = wid >> 1, wn = wid & 1;
    const int qd = lane >> 4, lm = lane & 15;

    const floatx4 zero4 = {0.f, 0.f, 0.f, 0.f};
    const int e0 = t * 8;
    const int r0 = e0 >> 5, c0 = e0 & 31;
    const int e1 = (256 + t) * 8;
    const int r1 = e1 >> 5, c1 = e1 & 31;

    const u16* Aab = jb.Aa + (size_t)m0 * K;
    const u16* Bab = jb.Ba + (size_t)n0 * K;

    if (jb.Ac) {
        // ---------------- dual mode ----------------
        floatx4 accA[4][4], accC[4][4];
#pragma unroll
        for (int i = 0; i < 4; i++)
#pragma unroll
            for (int j2 = 0; j2 < 4; j2++) { accA[i][j2] = zero4; accC[i][j2] = zero4; }
        const u16* Acb = jb.Ac + (size_t)m0 * K;
        const u16* Bcb = jb.Bc + (size_t)n0 * K;

        for (int k0 = 0; k0 < K; k0 += 32) {
            __syncthreads();
            gl_lds16(Aab + (size_t)r0 * K + k0 + c0, &Asa[e0]);
            gl_lds16(Aab + (size_t)r1 * K + k0 + c1, &Asa[e1]);
            gl_lds16(Acb + (size_t)r0 * K + k0 + c0, &Asc[e0]);
            gl_lds16(Acb + (size_t)r1 * K + k0 + c1, &Asc[e1]);
            gl_lds16(Bab + (size_t)r0 * K + k0 + c0, &Bsa[e0]);
            gl_lds16(Bab + (size_t)r1 * K + k0 + c1, &Bsa[e1]);
            gl_lds16(Bcb + (size_t)r0 * K + k0 + c0, &Bsc[e0]);
            gl_lds16(Bcb + (size_t)r1 * K + k0 + c1, &Bsc[e1]);
            __syncthreads();

            short8 aa[4], ac[4], ba[4], bc[4];
#pragma unroll
            for (int i = 0; i < 4; i++) {
                aa[i] = *(const short8*)&Asa[(wm * 64 + i * 16 + lm) * 32 + qd * 8];
                ac[i] = *(const short8*)&Asc[(wm * 64 + i * 16 + lm) * 32 + qd * 8];
                ba[i] = *(const short8*)&Bsa[(wn * 64 + i * 16 + lm) * 32 + qd * 8];
                bc[i] = *(const short8*)&Bsc[(wn * 64 + i * 16 + lm) * 32 + qd * 8];
            }
#pragma unroll
            for (int i = 0; i < 4; i++)
#pragma unroll
                for (int j2 = 0; j2 < 4; j2++) {
                    accA[i][j2] = __builtin_amdgcn_mfma_f32_16x16x32_bf16(aa[i], ba[j2], accA[i][j2], 0, 0, 0);
                    accC[i][j2] = __builtin_amdgcn_mfma_f32_16x16x32_bf16(ac[i], bc[j2], accC[i][j2], 0, 0, 0);
                }
        }

#pragma unroll
        for (int i = 0; i < 4; i++) {
            const int mb = m0 + wm * 64 + i * 16 + qd * 4;
            float lamv[4];
#pragma unroll
            for (int r = 0; r < 4; r++) lamv[r] = jb.lam[mb + r];
#pragma unroll
            for (int j2 = 0; j2 < 4; j2++) {
                const int col = n0 + wn * 64 + j2 * 16 + lm;
                const float bA = jb.biasA[col];
                const float bC = jb.biasC[col];
#pragma unroll
                for (int r = 0; r < 4; r++) {
                    const float va = accA[i][j2][r] + bA;
                    const float vc = accC[i][j2][r] + bC;
                    jb.out[(size_t)(mb + r) * 1024 + col] = f2bf(va + lamv[r] * (vc - va));
                }
            }
        }
    } else {
        // ---------------- single mode ----------------
        floatx4 acc[4][4];
#pragma unroll
        for (int i = 0; i < 4; i++)
#pragma unroll
            for (int j2 = 0; j2 < 4; j2++) acc[i][j2] = zero4;

        for (int k0 = 0; k0 < K; k0 += 32) {
            __syncthreads();
            gl_lds16(Aab + (size_t)r0 * K + k0 + c0, &Asa[e0]);
            gl_lds16(Aab + (size_t)r1 * K + k0 + c1, &Asa[e1]);
            gl_lds16(Bab + (size_t)r0 * K + k0 + c0, &Bsa[e0]);
            gl_lds16(Bab + (size_t)r1 * K + k0 + c1, &Bsa[e1]);
            __syncthreads();

            short8 af[4], bfg[4];
#pragma unroll
            for (int i = 0; i < 4; i++) {
                af[i]  = *(const short8*)&Asa[(wm * 64 + i * 16 + lm) * 32 + qd * 8];
                bfg[i] = *(const short8*)&Bsa[(wn * 64 + i * 16 + lm) * 32 + qd * 8];
            }
#pragma unroll
            for (int i = 0; i < 4; i++)
#pragma unroll
                for (int j2 = 0; j2 < 4; j2++)
                    acc[i][j2] = __builtin_amdgcn_mfma_f32_16x16x32_bf16(af[i], bfg[j2], acc[i][j2], 0, 0, 0);
        }

#pragma unroll
        for (int i = 0; i < 4; i++) {
            const int mb = m0 + wm * 64 + i * 16 + qd * 4;
#pragma unroll
            for (int j2 = 0; j2 < 4; j2++) {
                const int col = n0 + wn * 64 + j2 * 16 + lm;
                const float bv = jb.biasA[col];
#pragma unroll
                for (int r = 0; r < 4; r++)
                    jb.out[(size_t)(mb + r) * 1024 + col] = f2bf(acc[i][j2][r] + bv);
            }
        }
    }
}

// =====================================================================
// gemm64: C_f32[M,1024] = A_bf16[M,1024] @ Bt[1024][1024] + bias
// 64x128 tile -> grid (8, 64) = 512 blocks (2/CU). 12 KB LDS.
// =====================================================================
__global__ __launch_bounds__(256, 4) void gemm64(const u16* __restrict__ A,
                                                 const u16* __restrict__ Bt,
                                                 const float* __restrict__ bias,
                                                 float* __restrict__ C) {
    __shared__ u16 As[64 * 32];
    __shared__ u16 Bs[128 * 32];
    const int K = 1024;
    const int m0 = blockIdx.y * 64;
    const int n0 = blockIdx.x * 128;
    const int t = threadIdx.x;
    const int lane = t & 63;
    const int wid = t >> 6;
    const int wm = wid >> 1, wn = wid & 1;
    const int qd = lane >> 4, lm = lane & 15;

    const floatx4 zero4 = {0.f, 0.f, 0.f, 0.f};
    floatx4 acc[2][4];
#pragma unroll
    for (int i = 0; i < 2; i++)
#pragma unroll
        for (int j2 = 0; j2 < 4; j2++) acc[i][j2] = zero4;

    const u16* Ab = A + (size_t)m0 * K;
    const u16* Bb = Bt + (size_t)n0 * K;
    const int e0 = t * 8;
    const int r0 = e0 >> 5, c0 = e0 & 31;           // A: rows 0..63
    const int e1 = (256 + t) * 8;
    const int r1 = e1 >> 5, c1 = e1 & 31;           // B: rows 64..127

    for (int k0 = 0; k0 < K; k0 += 32) {
        __syncthreads();
        gl_lds16(Ab + (size_t)r0 * K + k0 + c0, &As[e0]);
        gl_lds16(Bb + (size_t)r0 * K + k0 + c0, &Bs[e0]);
        gl_lds16(Bb + (size_t)r1 * K + k0 + c1, &Bs[e1]);
        __syncthreads();

        short8 af[2], bfg[4];
#pragma unroll
        for (int i = 0; i < 2; i++)
            af[i] = *(const short8*)&As[(wm * 32 + i * 16 + lm) * 32 + qd * 8];
#pragma unroll
        for (int j2 = 0; j2 < 4; j2++)
            bfg[j2] = *(const short8*)&Bs[(wn * 64 + j2 * 16 + lm) * 32 + qd * 8];
#pragma unroll
        for (int i = 0; i < 2; i++)
#pragma unroll
            for (int j2 = 0; j2 < 4; j2++)
                acc[i][j2] = __builtin_amdgcn_mfma_f32_16x16x32_bf16(af[i], bfg[j2], acc[i][j2], 0, 0, 0);
    }

#pragma unroll
    for (int i = 0; i < 2; i++) {
        const int mb = m0 + wm * 32 + i * 16 + qd * 4;
#pragma unroll
        for (int j2 = 0; j2 < 4; j2++) {
            const int col = n0 + wn * 64 + j2 * 16 + lm;
            const float bv = bias[col];
#pragma unroll
            for (int r = 0; r < 4; r++)
                C[(size_t)(mb + r) * 1024 + col] = acc[i][j2][r] + bv;
        }
    }
}

// =====================================================================
// attention v4: split-K flash, wave = 64 q-rows, reg-prefetch dbuf.
// grid (2048/256=8 qtiles, 32 bh, 2 splits). block 256 = 4 waves.
// LDS: Ks/Vs 64x72 + Ps 4x64x72 = 55296 B -> 2 blocks/CU.
// =====================================================================
__global__ __launch_bounds__(256, 2) void attn4(
    const u16* __restrict__ Q, const u16* __restrict__ Kk,
    const u16* __restrict__ Vtg, float* __restrict__ ctxp,
    float* __restrict__ lp) {
    __shared__ u16 Ks[64 * 72];
    __shared__ u16 Vs[64 * 72];
    __shared__ u16 Ps[4 * 64 * 72];

    const int bh = blockIdx.y, b = bh >> 4, h = bh & 15;
    const int sp = blockIdx.z;
    const int base = b * 1024 + h * 64;
    const int t = threadIdx.x, lane = t & 63, w = t >> 6;
    const int qd = lane >> 4, lm = lane & 15;
    const int q0w = blockIdx.x * 256 + w * 64;      // wave's first q row

    // Q B-frags for 4 q-groups of 16
    short8 qf[4][2];
#pragma unroll
    for (int qh = 0; qh < 4; qh++) {
        const u16* qr = Q + (size_t)(q0w + qh * 16 + lm) * 2048 + base;
#pragma unroll
        for (int c = 0; c < 2; c++)
            qf[qh][c] = *(const short8*)(qr + c * 32 + qd * 8);
    }

    const floatx4 zero4 = {0.f, 0.f, 0.f, 0.f};
    floatx4 ctx[4][4];
#pragma unroll
    for (int qh = 0; qh < 4; qh++)
#pragma unroll
        for (int g = 0; g < 4; g++) ctx[qh][g] = zero4;
    float lpart[4] = {0.f, 0.f, 0.f, 0.f};

    u16* Pw = &Ps[w * 64 * 72];
    const float C = 0.18033688011112042f;   // log2(e)/sqrt(64)

    // staging: thread moves 2x16B K + 2x16B V per tile
    const int sr = t >> 3, sc = (t & 7) * 8;
    const u16* ksrc = Kk + (size_t)(sp * 1024 + sr) * 2048 + base + sc;
    const u16* vsrc = Vtg + ((size_t)bh * 64 + sr) * 2048 + sp * 1024 + sc;
    u16* kdst0 = &Ks[sr * 72 + sc];
    u16* kdst1 = &Ks[(sr + 32) * 72 + sc];
    u16* vdst0 = &Vs[sr * 72 + sc];
    u16* vdst1 = &Vs[(sr + 32) * 72 + sc];

    // prefetch tile 0
    short8 ka0 = *(const short8*)ksrc;
    short8 ka1 = *(const short8*)(ksrc + (size_t)32 * 2048);
    short8 va0 = *(const short8*)vsrc;
    short8 va1 = *(const short8*)(vsrc + (size_t)32 * 2048);

    for (int kt = 0; kt < 16; kt++) {
        __syncthreads();
        *(short8*)kdst0 = ka0;
        *(short8*)kdst1 = ka1;
        *(short8*)vdst0 = va0;
        *(short8*)vdst1 = va1;
        __syncthreads();
        // prefetch next tile; retires during compute below
        if (kt < 15) {
            ksrc += (size_t)64 * 2048;
            vsrc += 64;
            ka0 = *(const short8*)ksrc;
            ka1 = *(const short8*)(ksrc + (size_t)32 * 2048);
            va0 = *(const short8*)vsrc;
            va1 = *(const short8*)(vsrc + (size_t)32 * 2048);
        }

        // --- S^T = K.Q^T, exp, vectorized P store ---
#pragma unroll
        for (int g = 0; g < 4; g++) {
            const short8 kf0 = *(const short8*)&Ks[(g * 16 + lm) * 72 + qd * 8];
            const short8 kf1 = *(const short8*)&Ks[(g * 16 + lm) * 72 + 32 + qd * 8];
#pragma unroll
            for (int qh = 0; qh < 4; qh++) {
                floatx4 st = zero4;
                st = __builtin_amdgcn_mfma_f32_16x16x32_bf16(kf0, qf[qh][0], st, 0, 0, 0);
                st = __builtin_amdgcn_mfma_f32_16x16x32_bf16(kf1, qf[qh][1], st, 0, 0, 0);
                const float p0 = exp2f(st[0] * C);
                const float p1 = exp2f(st[1] * C);
                const float p2 = exp2f(st[2] * C);
                const float p3 = exp2f(st[3] * C);
                lpart[qh] += (p0 + p1) + (p2 + p3);
                uint2v pw;
                pw[0] = pk2bf(p0, p1);
                pw[1] = pk2bf(p2, p3);
                *(uint2v*)&Pw[(qh * 16 + lm) * 72 + g * 16 + qd * 4] = pw;
            }
        }

        // --- ctx += P.V ---
        short8 pa[4][2];
#pragma unroll
        for (int qh = 0; qh < 4; qh++)
#pragma unroll
            for (int c = 0; c < 2; c++)
                pa[qh][c] = *(const short8*)&Pw[(qh * 16 + lm) * 72 + c * 32 + qd * 8];
#pragma unroll
        for (int g = 0; g < 4; g++) {
            const short8 vb0 = *(const short8*)&Vs[(g * 16 + lm) * 72 + qd * 8];
            const short8 vb1 = *(const short8*)&Vs[(g * 16 + lm) * 72 + 32 + qd * 8];
#pragma unroll
            for (int qh = 0; qh < 4; qh++) {
                ctx[qh][g] = __builtin_amdgcn_mfma_f32_16x16x32_bf16(pa[qh][0], vb0, ctx[qh][g], 0, 0, 0);
                ctx[qh][g] = __builtin_amdgcn_mfma_f32_16x16x32_bf16(pa[qh][1], vb1, ctx[qh][g], 0, 0, 0);
            }
        }
    }

    // epilogue: store un-normalized partials
    float* cbase = ctxp + (size_t)sp * 4194304;
#pragma unroll
    for (int qh = 0; qh < 4; qh++) {
        float l = lpart[qh];
        l += __shfl_xor(l, 16);
        l += __shfl_xor(l, 32);
        if (lane < 16)
            lp[(size_t)sp * 65536 + bh * 2048 + q0w + qh * 16 + lane] = l;
#pragma unroll
        for (int r = 0; r < 4; r++) {
            const int srow = q0w + qh * 16 + qd * 4 + r;
            float* orow = cbase + (size_t)srow * 2048 + base;
#pragma unroll
            for (int g = 0; g < 4; g++)
                orow[g * 16 + lm] = ctx[qh][g][r];
        }
    }
}

// =====================================================================
// merge: out_bf16 = (ctx0 + ctx1) / (l0 + l1), elementwise over 4M
// =====================================================================
__global__ __launch_bounds__(256) void merge(const float* __restrict__ ctxp,
                                             const float* __restrict__ lp,
                                             u16* __restrict__ out) {
    const size_t idx = ((size_t)blockIdx.x * 256 + threadIdx.x) * 4;
    const floatx4 a = *(const floatx4*)(ctxp + idx);
    const floatx4 c = *(const floatx4*)(ctxp + 4194304 + idx);
    const int srow = (int)(idx >> 11);
    const int rem = (int)(idx & 2047);
    const int bh = rem >> 6;
    const float l = lp[bh * 2048 + srow] + lp[65536 + bh * 2048 + srow];
    const float inv = 1.0f / l;
    ushort4v o;
    const unsigned int lo = pk2bf((a[0] + c[0]) * inv, (a[1] + c[1]) * inv);
    const unsigned int hi = pk2bf((a[2] + c[2]) * inv, (a[3] + c[3]) * inv);
    o[0] = (u16)(lo & 0xffff); o[1] = (u16)(lo >> 16);
    o[2] = (u16)(hi & 0xffff); o[3] = (u16)(hi >> 16);
    *(ushort4v*)(out + idx) = o;
}

// =====================================================================
// host orchestration
// =====================================================================
extern "C" void kernel_launch(void* const* d_in, const int* in_sizes, int n_in,
                              void* d_out, int out_size, void* d_ws, size_t ws_size,
                              hipStream_t stream) {
    const float* qx = (const float*)d_in[0];
    const float* kx = (const float*)d_in[1];
    const float* vx = (const float*)d_in[2];
    const float* qc = (const float*)d_in[3];
    const float* kc = (const float*)d_in[4];
    const float* W_qx = (const float*)d_in[5];   const float* b_qx = (const float*)d_in[6];
    const float* W_kx = (const float*)d_in[7];   const float* b_kx = (const float*)d_in[8];
    const float* W_vx = (const float*)d_in[9];   const float* b_vx = (const float*)d_in[10];
    const float* W_qc = (const float*)d_in[11];  const float* b_qc = (const float*)d_in[12];
    const float* W_kc = (const float*)d_in[13];  const float* b_kc = (const float*)d_in[14];
    const float* W_out = (const float*)d_in[15]; const float* b_out = (const float*)d_in[16];
    const float* W_Vqx = (const float*)d_in[17]; const float* b_Vqx = (const float*)d_in[18];
    const float* W_Vqc = (const float*)d_in[19]; const float* b_Vqc = (const float*)d_in[20];
    const float* W_Vkx = (const float*)d_in[21]; const float* b_Vkx = (const float*)d_in[22];
    const float* W_Vkc = (const float*)d_in[23]; const float* b_Vkc = (const float*)d_in[24];

    char* ws = (char*)d_ws;
    const size_t NT = 4194304;               // S*B*D elems
    const size_t MB = 1048576;
    u16* Xb[5];
    for (int i = 0; i < 5; i++) Xb[i] = (u16*)(ws + (size_t)i * NT * 2);
    u16* Wt[6];
    for (int i = 0; i < 6; i++) Wt[i] = (u16*)(ws + 40 * MB + (size_t)i * 2 * MB);
    u16* Pv    = (u16*)(ws + 52 * MB);
    u16* qg    = (u16*)(ws + 60 * MB);
    u16* kg    = (u16*)(ws + 68 * MB);
    u16* ctxbf = (u16*)(ws + 76 * MB);
    float* wfused = (float*)(ws + 84 * MB);            // 4 x 1024
    float* dots   = (float*)(ws + 84 * MB + 16384);    // 4 x 4096
    float* lam    = (float*)(ws + 84 * MB + 16384 + 65536);   // 2 x 4096
    float* l_part = (float*)(ws + 84 * MB + 16384 + 65536 + 32768); // 2 x 32 x 2048
    float* ctxp = (float*)ws;                 // 32 MB, aliases Xb[0..3]
    u16* Vtg    = (u16*)(ws + 32 * MB);       // 8 MB, aliases Xb[4]

    // 1. fused gating weight vectors: w_z = W_z @ W_V_z
    WFuseJobs wf;
    wf.W[0] = W_qx; wf.wv[0] = W_Vqx; wf.out[0] = wfused;
    wf.W[1] = W_qc; wf.wv[1] = W_Vqc; wf.out[1] = wfused + 1024;
    wf.W[2] = W_kx; wf.wv[2] = W_Vkx; wf.out[2] = wfused + 2048;
    wf.W[3] = W_kc; wf.wv[3] = W_Vkc; wf.out[3] = wfused + 3072;
    wfuse<<<dim3(64, 4), 256, 0, stream>>>(wf);

    // 2. cast inputs to bf16 + fused lambda row-dots
    CastJobs cj;
    const float* srcs[5] = {qx, kx, vx, qc, kc};
    for (int i = 0; i < 5; i++) { cj.src[i] = srcs[i]; cj.dst[i] = Xb[i]; cj.w[i] = nullptr; cj.dot[i] = nullptr; }
    cj.w[0] = wfused;        cj.dot[0] = dots;            // qx . w1
    cj.w[3] = wfused + 1024; cj.dot[3] = dots + 4096;     // qc . w2
    cj.w[1] = wfused + 2048; cj.dot[1] = dots + 8192;     // kx . w3
    cj.w[4] = wfused + 3072; cj.dot[4] = dots + 12288;    // kc . w4
    castbf<<<dim3(4096, 5), 256, 0, stream>>>(cj);

    // 3. lambdas
    LamJobs lj;
    lj.dA[0] = dots;        lj.dB[0] = dots + 4096;
    lj.b1[0] = b_qx; lj.b2[0] = b_qc; lj.wv1[0] = W_Vqx; lj.wv2[0] = W_Vqc;
    lj.s1[0] = b_Vqx; lj.s2[0] = b_Vqc; lj.lam[0] = lam;
    lj.dA[1] = dots + 8192; lj.dB[1] = dots + 12288;
    lj.b1[1] = b_kx; lj.b2[1] = b_kc; lj.wv1[1] = W_Vkx; lj.wv2[1] = W_Vkc;
    lj.s1[1] = b_Vkx; lj.s2[1] = b_Vkc; lj.lam[1] = lam + 4096;
    lamk<<<dim3(16, 2), 256, 0, stream>>>(lj);

    // 4. transpose + cast weights
    WTJobs wj;
    const float* wsrc[6] = {W_qx, W_kx, W_vx, W_qc, W_kc, W_out};
    for (int i = 0; i < 6; i++) { wj.src[i] = wsrc[i]; wj.dst[i] = Wt[i]; }
    wtrans<<<dim3(32, 32, 6), 256, 0, stream>>>(wj);

    // 5. all projections in ONE launch: q-dual, k-dual, v-single
    PJobs pj;
    pj.j[0].Aa = Xb[0]; pj.j[0].Ac = Xb[3]; pj.j[0].Ba = Wt[0]; pj.j[0].Bc = Wt[3];
    pj.j[0].biasA = b_qx; pj.j[0].biasC = b_qc; pj.j[0].lam = lam;        pj.j[0].out = qg;
    pj.j[1].Aa = Xb[1]; pj.j[1].Ac = Xb[4]; pj.j[1].Ba = Wt[1]; pj.j[1].Bc = Wt[4];
    pj.j[1].biasA = b_kx; pj.j[1].biasC = b_kc; pj.j[1].lam = lam + 4096; pj.j[1].out = kg;
    pj.j[2].Aa = Xb[2]; pj.j[2].Ac = nullptr; pj.j[2].Ba = Wt[2]; pj.j[2].Bc = nullptr;
    pj.j[2].biasA = b_vx; pj.j[2].biasC = nullptr; pj.j[2].lam = nullptr; pj.j[2].out = Pv;
    projall<<<dim3(8, 32, 3), 256, 0, stream>>>(pj);

    // 6. transpose V
    vtrans<<<dim3(64, 2, 32), 256, 0, stream>>>(Pv, Vtg);

    // 7. attention (split-K x2, 64 q/wave, reg-prefetch)
    attn4<<<dim3(8, 32, 2), 256, 0, stream>>>(qg, kg, Vtg, ctxp, l_part);

    // 8. merge partials -> ctx bf16
    merge<<<4096, 256, 0, stream>>>(ctxp, l_part, ctxbf);

    // 9. output projection -> d_out (fp32), 64-row tiles for occupancy
    gemm64<<<dim3(8, 64), 256, 0, stream>>>(ctxbf, Wt[5], b_out, (float*)d_out);
}